// Round 11
// baseline (327.203 us; speedup 1.0000x reference)
//
#include <hip/hip_runtime.h>
#include <math.h>

typedef unsigned short ushort_t;
typedef __attribute__((ext_vector_type(8))) short short8x;
typedef __attribute__((ext_vector_type(4))) float f32x4;

#define CSHIFT 9        // coarse bucket = 512 nodes
#define CC 12288        // entries per coarse bucket (mean ~8163, +45 sigma)
#define EPB 4096        // edges per pass-A block
#define ECAP 1024       // staged entries per fine bucket (mean ~512)
#define NCMAX 128       // max coarse buckets (N<65536 -> <=128)

#define C06L2E 0.8656170245333781f   // 0.6 * log2(e)
#define C04L2E 0.5770780163555854f   // 0.4 * log2(e)

__device__ __forceinline__ unsigned f2bf(float f) {
  unsigned u = __float_as_uint(f);
  u += 0x7fff + ((u >> 16) & 1);
  return u >> 16;
}
__device__ __forceinline__ float bf2f(ushort_t u) {
  return __uint_as_float(((unsigned)u) << 16);
}
// sum over the 8-lane half of each 16-lane DPP row (pure VALU, no LDS pipe)
__device__ __forceinline__ float dpp_red8(float v) {
  v += __int_as_float(__builtin_amdgcn_update_dpp(0, __float_as_int(v), 0xB1, 0xF, 0xF, true));   // quad_perm xor1
  v += __int_as_float(__builtin_amdgcn_update_dpp(0, __float_as_int(v), 0x4E, 0xF, 0xF, true));   // quad_perm xor2
  v += __int_as_float(__builtin_amdgcn_update_dpp(0, __float_as_int(v), 0x141, 0xF, 0xF, true));  // row_half_mirror
  return v;
}
__device__ __forceinline__ float dpp_red16(float v) {
  v = dpp_red8(v);
  v += __int_as_float(__builtin_amdgcn_update_dpp(0, __float_as_int(v), 0x140, 0xF, 0xF, true));  // row_mirror
  return v;
}

struct GArgs {
  const float* Wl[2];
  const float* bl[2];
  const float* Wr[2];
  const float* br[2];
  const float* Wres[2];
  const float* bias[2];
};

// identity column layout, col in [0,640): dir=col/320; cc<128: Wl, <256: Wr, else Wres
__device__ __forceinline__ float wval1(const GArgs& ga, int col, int k) {
  int dir = col >= 320 ? 1 : 0;
  int cc = col - dir * 320;
  return cc < 128 ? ga.Wl[dir][k * 128 + cc]
       : cc < 256 ? ga.Wr[dir][k * 128 + (cc - 128)]
                  : ga.Wres[dir][k * 64 + (cc - 256)];
}
__device__ __forceinline__ float bval(const GArgs& ga, int col) {
  int dir = col >= 320 ? 1 : 0;
  int cc = col - dir * 320;
  return cc < 128 ? ga.bl[dir][cc]
       : cc < 256 ? ga.br[dir][cc - 128]
                  : ga.bias[dir][cc - 256];
}

// ------------------------- weight packing ----------------------------------
// WT1[640][128], WT2[640][128] (block-diag), plus folded att-matvec weights:
// WS1/WS2 [128][4] f32 (t = dir*2 + head), sb[8] = att-dot-bias consts.

__global__ __launch_bounds__(128) void pack_kernel(
    GArgs g1, GArgs g2, const float* __restrict__ a1d0,
    const float* __restrict__ a1d1, const float* __restrict__ a2d0,
    const float* __restrict__ a2d1, ushort_t* __restrict__ WT1,
    ushort_t* __restrict__ WT2, float* __restrict__ bc1,
    float* __restrict__ bc2, float* __restrict__ WS1,
    float* __restrict__ WS2, float* __restrict__ sb) {
  int b = blockIdx.x;
  int k = threadIdx.x;
  if (b < 640) {
    WT1[b * 128 + k] = (ushort_t)f2bf(wval1(g1, b, k));
  } else if (b < 1280) {
    int c = b - 640;
    int dir = c >= 320 ? 1 : 0;
    int cc = c - dir * 320;
    float v = 0.f;
    if ((k >> 6) == dir) {
      int k2 = k & 63;
      v = cc < 128 ? g2.Wl[dir][k2 * 128 + cc]
        : cc < 256 ? g2.Wr[dir][k2 * 128 + (cc - 128)]
                   : g2.Wres[dir][k2 * 64 + (cc - 256)];
    }
    WT2[c * 128 + k] = (ushort_t)f2bf(v);
  } else if (b == 1280) {
    for (int c = k; c < 640; c += 128) {
      bc1[c] = bval(g1, c);
      bc2[c] = bval(g2, c);
    }
  } else {
    // folded matvec weights: WS[k][t] = sum_c att[dir][h*64+c] * Wl[dir][k,h*64+c]
    const float* att1[2] = {a1d0, a1d1};
    const float* att2[2] = {a2d0, a2d1};
#pragma unroll
    for (int t = 0; t < 4; ++t) {
      int dir = t >> 1, h = t & 1;
      float s1 = 0.f;
      for (int c = 0; c < 64; ++c)
        s1 += att1[dir][h * 64 + c] * g1.Wl[dir][k * 128 + h * 64 + c];
      WS1[k * 4 + t] = s1;
      float s2 = 0.f;
      if ((k >> 6) == dir) {
        int k2 = k & 63;
        for (int c = 0; c < 64; ++c)
          s2 += att2[dir][h * 64 + c] * g2.Wl[dir][k2 * 128 + h * 64 + c];
      }
      WS2[k * 4 + t] = s2;
    }
    if (k < 8) {
      int t = k & 3;
      int dir = t >> 1, h = t & 1;
      const float* att = (k < 4) ? (dir ? a1d1 : a1d0) : (dir ? a2d1 : a2d0);
      const float* bl = (k < 4) ? g1.bl[dir] : g2.bl[dir];
      float s = 0.f;
      for (int c = 0; c < 64; ++c) s += att[h * 64 + c] * bl[h * 64 + c];
      sb[k] = s;
    }
  }
}

// ------------------------- bf16 MFMA GEMM body -----------------------------

template <int AF32>
__device__ __forceinline__ void gemm_body(const float* Af, const ushort_t* Ab,
                                          const ushort_t* WT, const float* bc,
                                          ushort_t* Y, int N, int rb, int cb,
                                          ushort_t* lds) {
  const int tid = threadIdx.x;
  const int lane = tid & 63;
  const int w = tid >> 6;
  const int m0 = rb * 64;
  const int cbase = cb * 128 + w * 32;

#pragma unroll
  for (int c = 0; c < 4; ++c) {
    int Lb = (tid + c * 256) * 16;
    int row = Lb >> 8, within = Lb & 255;
    int so = within ^ ((row & 7) << 4);
    int grow = m0 + row;
    if (grow >= N) grow = N - 1;
    if (AF32) {
      const float* src = Af + (size_t)grow * 128 + (so >> 1);
      float4 a = *(const float4*)src;
      float4 b = *(const float4*)(src + 4);
      uint4 o;
      o.x = f2bf(a.x) | (f2bf(a.y) << 16);
      o.y = f2bf(a.z) | (f2bf(a.w) << 16);
      o.z = f2bf(b.x) | (f2bf(b.y) << 16);
      o.w = f2bf(b.z) | (f2bf(b.w) << 16);
      ((uint4*)lds)[tid + c * 256] = o;
    } else {
      ((uint4*)lds)[tid + c * 256] = *(const uint4*)(Ab + (size_t)grow * 128 + (so >> 1));
    }
  }

  short8x bf[4][2];
#pragma unroll
  for (int ks = 0; ks < 4; ++ks)
#pragma unroll
    for (int ns = 0; ns < 2; ++ns) {
      int col = cbase + ns * 16 + (lane & 15);
      bf[ks][ns] = *(const short8x*)(WT + (size_t)col * 128 + ks * 32 + (lane >> 4) * 8);
    }

  __syncthreads();

  f32x4 z = {0.f, 0.f, 0.f, 0.f};
  f32x4 acc[4][2];
#pragma unroll
  for (int ms = 0; ms < 4; ++ms) {
    acc[ms][0] = z;
    acc[ms][1] = z;
  }
#pragma unroll
  for (int ks = 0; ks < 4; ++ks) {
    short8x af[4];
#pragma unroll
    for (int ms = 0; ms < 4; ++ms) {
      int row = ms * 16 + (lane & 15);
      int byte = row * 256 + ((ks * 64 + (lane >> 4) * 16) ^ ((row & 7) << 4));
      af[ms] = *(const short8x*)((const char*)lds + byte);
    }
#pragma unroll
    for (int ms = 0; ms < 4; ++ms) {
      acc[ms][0] = __builtin_amdgcn_mfma_f32_16x16x32_bf16(af[ms], bf[ks][0], acc[ms][0], 0, 0, 0);
      acc[ms][1] = __builtin_amdgcn_mfma_f32_16x16x32_bf16(af[ms], bf[ks][1], acc[ms][1], 0, 0, 0);
    }
  }

#pragma unroll
  for (int ms = 0; ms < 4; ++ms)
#pragma unroll
    for (int ns = 0; ns < 2; ++ns) {
      int col = cbase + ns * 16 + (lane & 15);
      float bv = bc[col];
#pragma unroll
      for (int r = 0; r < 4; ++r) {
        int grow = m0 + ms * 16 + (lane >> 4) * 4 + r;
        if (grow < N) Y[(size_t)grow * 640 + col] = (ushort_t)f2bf(acc[ms][ns][r] + bv);
      }
    }
}

// ------------------ K matvec role (shared): K[n][t]=exp2(C6*(A.WS+sb)) -----
// 16 lanes per node; AF32: A row f32 (layer1 x) else bf16 (A2).

template <int AF32>
__device__ __forceinline__ void kmat_body(const float* Af, const ushort_t* Ab,
                                          const float* __restrict__ WS,
                                          const float* __restrict__ sbp,
                                          ushort_t* __restrict__ K, int kb, int N) {
  const int t = threadIdx.x;
  const int jj = t & 15;
  float wsr[8][4];
#pragma unroll
  for (int q = 0; q < 8; ++q) {
    float4 w = *(const float4*)(WS + (jj * 8 + q) * 4);
    wsr[q][0] = w.x; wsr[q][1] = w.y; wsr[q][2] = w.z; wsr[q][3] = w.w;
  }
  float sb4[4] = {sbp[0], sbp[1], sbp[2], sbp[3]};
#pragma unroll
  for (int it = 0; it < 4; ++it) {
    int n = kb * 64 + it * 16 + (t >> 4);
    if (n >= N) continue;
    float xv[8];
    if (AF32) {
      const float* src = Af + (size_t)n * 128 + jj * 8;
      float4 a = *(const float4*)src;
      float4 b = *(const float4*)(src + 4);
      xv[0] = a.x; xv[1] = a.y; xv[2] = a.z; xv[3] = a.w;
      xv[4] = b.x; xv[5] = b.y; xv[6] = b.z; xv[7] = b.w;
    } else {
      short8x v = *(const short8x*)(Ab + (size_t)n * 128 + jj * 8);
#pragma unroll
      for (int q = 0; q < 8; ++q) xv[q] = bf2f((ushort_t)v[q]);
    }
    float s[4] = {0.f, 0.f, 0.f, 0.f};
#pragma unroll
    for (int q = 0; q < 8; ++q)
#pragma unroll
      for (int t4 = 0; t4 < 4; ++t4) s[t4] = fmaf(xv[q], wsr[q][t4], s[t4]);
#pragma unroll
    for (int t4 = 0; t4 < 4; ++t4) s[t4] = dpp_red16(s[t4]);
    if (jj == 0) {
      unsigned kk[4];
#pragma unroll
      for (int t4 = 0; t4 < 4; ++t4)
        kk[t4] = f2bf(__builtin_amdgcn_exp2f(C06L2E * (s[t4] + sb4[t4])));
      uint2 pk;
      pk.x = kk[0] | (kk[1] << 16);
      pk.y = kk[2] | (kk[3] << 16);
      *(uint2*)(K + (size_t)n * 4) = pk;
    }
  }
}

// ---------------- fused front-end: coarse-bin | gemm1 | copy_x | K1 --------

__global__ __launch_bounds__(256) void k_front(
    const float* __restrict__ x, const int* __restrict__ ei, int E, int N,
    int* __restrict__ gc0, int* __restrict__ gc1, int* __restrict__ ctail0,
    int* __restrict__ ctail1, const ushort_t* __restrict__ WT1,
    const float* __restrict__ bc1, const float* __restrict__ WS1,
    const float* __restrict__ sb, ushort_t* __restrict__ K1,
    ushort_t* __restrict__ Y, float* __restrict__ out, int nbinA, int ngemm,
    int nrow, int ncopy) {
  __shared__ ushort_t lds[8192];
  const int bid = blockIdx.x;
  const int t = threadIdx.x;
  if (bid < nbinA) {
    int* h0 = (int*)lds;
    int* h1 = h0 + NCMAX;
    int* b0 = h1 + NCMAX;
    int* b1 = b0 + NCMAX;
    const int e0 = bid * EPB;
    const int e1 = min(e0 + EPB, E);
    for (int i = t; i < NCMAX; i += 256) {
      h0[i] = 0;
      h1[i] = 0;
    }
    __syncthreads();
    for (int i = e0 + t; i < e1; i += 256) {
      int s = ei[i], d = ei[E + i];
      atomicAdd(&h0[d >> CSHIFT], 1);
      atomicAdd(&h1[s >> CSHIFT], 1);
    }
    __syncthreads();
    for (int c = t; c < NCMAX; c += 256) {
      int n0 = h0[c], n1 = h1[c];
      b0[c] = n0 ? atomicAdd(&ctail0[c], n0) : 0;
      b1[c] = n1 ? atomicAdd(&ctail1[c], n1) : 0;
      h0[c] = 0;
      h1[c] = 0;
    }
    __syncthreads();
    for (int i = e0 + t; i < e1; i += 256) {
      int s = ei[i], d = ei[E + i];
      int c0 = d >> CSHIFT;
      int p0 = b0[c0] + atomicAdd(&h0[c0], 1);
      if (p0 < CC) gc0[c0 * CC + p0] = (s << 16) | d;
      int c1 = s >> CSHIFT;
      int p1 = b1[c1] + atomicAdd(&h1[c1], 1);
      if (p1 < CC) gc1[c1 * CC + p1] = (d << 16) | s;
    }
  } else if (bid < nbinA + ngemm) {
    int gb = bid - nbinA;
    gemm_body<1>(x, nullptr, WT1, bc1, Y, N, gb % nrow, gb / nrow, lds);
  } else if (bid < nbinA + ngemm + ncopy) {
    int i = (bid - nbinA - ngemm) * 256 + t;
    if (i < N * 32) {
      float4 v = ((const float4*)x)[i];
      ((float4*)out)[(size_t)(i >> 5) * 64 + 32 + (i & 31)] = v;
    }
  } else {
    kmat_body<1>(x, nullptr, WS1, sb, K1, bid - nbinA - ngemm - ncopy, N);
  }
}

// ---------------------------- layer-2 GEMM (+K2 role) ----------------------

__global__ __launch_bounds__(256) void gemm2_kernel(const ushort_t* __restrict__ A,
                                                    const ushort_t* __restrict__ WT,
                                                    const float* __restrict__ bc,
                                                    const float* __restrict__ WS2,
                                                    const float* __restrict__ sb,
                                                    ushort_t* __restrict__ K2,
                                                    ushort_t* __restrict__ Y, int N) {
  __shared__ ushort_t lds[8192];
  if (blockIdx.y < 5) {
    gemm_body<0>(nullptr, A, WT, bc, Y, N, blockIdx.x, blockIdx.y, lds);
  } else {
    kmat_body<0>(nullptr, A, WS2, sb + 4, K2, blockIdx.x, N);
  }
}

// -------- fused aggregation: one block per 32-node fine bucket -------------
// lrelu decomposition: wgt = exp2(sum 0.4*L2E*att*|xi+xj|) * K_j, with the
// per-i factor dropped (softmax-invariant). K gathered from L2-resident array.

template <int MODE>  // 0: L1 (LayerNorm, bf16 out [N][128]), 1: L2 (f32 out [N][256])
__global__ __launch_bounds__(256) void agg_bucket(
    const ushort_t* __restrict__ Y, const int* __restrict__ gc0,
    const int* __restrict__ gc1, const int* __restrict__ ctail0,
    const int* __restrict__ ctail1, const ushort_t* __restrict__ Kv,
    const float* __restrict__ attA, const float* __restrict__ attB,
    const float* __restrict__ lng0, const float* __restrict__ lnb0,
    const float* __restrict__ lng1, const float* __restrict__ lnb1,
    void* __restrict__ outp, int N) {
  __shared__ int ebuf[ECAP];
  __shared__ int lnbr[ECAP + 8];  // raw neighbor indices + pad
  __shared__ int hist[32], offs[32], cur[32];
  __shared__ int ecnt;
  const int fb = blockIdx.x;
  const int cb = fb >> 4;
  const int dir = blockIdx.y;
  const int t = threadIdx.x;
  const int* gc = dir ? gc1 : gc0;
  const int* ctail = dir ? ctail1 : ctail0;
  const float* att = dir ? attB : attA;

  for (int i = t; i < ECAP + 8; i += 256) lnbr[i] = 0;
  if (t < 32) {
    hist[t] = 0;
    cur[t] = 0;
  }
  if (t == 64) ecnt = 0;
  __syncthreads();

  {
    const int cntc = min(ctail[cb], CC);
    const int* src = gc + cb * CC;
    for (int i = t; i < cntc; i += 256) {
      int e = src[i];
      if (((e & 0xFFFF) >> 5) == fb) {
        int idx = atomicAdd(&ecnt, 1);
        if (idx < ECAP) ebuf[idx] = e;
      }
    }
  }
  __syncthreads();
  const int tot = min(ecnt, ECAP);
  for (int i = t; i < tot; i += 256) atomicAdd(&hist[ebuf[i] & 31], 1);
  __syncthreads();
  if (t < 32) {
    int v = hist[t], inc = v;
#pragma unroll
    for (int o = 1; o < 32; o <<= 1) {
      int u = __shfl_up(inc, o);
      if (t >= o) inc += u;
    }
    offs[t] = inc - v;
  }
  __syncthreads();
  for (int i = t; i < tot; i += 256) {
    int e = ebuf[i];
    int r = e & 31;
    lnbr[offs[r] + atomicAdd(&cur[r], 1)] = (int)((unsigned)e >> 16);
  }
  __syncthreads();

  const int wv = t >> 6, lane = t & 63, g = lane >> 4, jj = lane & 15;
  float av[8];
  {
    float4 a0 = *(const float4*)(att + jj * 8);
    float4 a1 = *(const float4*)(att + jj * 8 + 4);
    av[0] = a0.x * C04L2E; av[1] = a0.y * C04L2E; av[2] = a0.z * C04L2E; av[3] = a0.w * C04L2E;
    av[4] = a1.x * C04L2E; av[5] = a1.y * C04L2E; av[6] = a1.z * C04L2E; av[7] = a1.w * C04L2E;
  }
  const char* Yb = (const char*)Y + dir * 640 + jj * 16;  // + j*1280 -> xl chans
  const int koff = dir * 2 + (jj >> 3);                   // K[n][dir*2+h]

  for (int r = wv; r < 32; r += 4) {
    const int n = fb * 32 + r;
    if (n >= N) break;
    const char* rowp = (const char*)Y + (size_t)n * 1280 + dir * 640;

    float xi[8];
    {
      short8x v = *(const short8x*)(rowp + 256 + jj * 16);  // xr block
#pragma unroll
      for (int q = 0; q < 8; ++q) xi[q] = bf2f((ushort_t)v[q]);
    }
    float d = 0.f;
    float acc[8];
#pragma unroll
    for (int q = 0; q < 8; ++q) acc[q] = 0.f;

    const int beg = offs[r], deg = hist[r];
    if (deg > 0) {
      int jc = lnbr[beg + g];
      short8x vj = *(const short8x*)(Yb + (size_t)(unsigned)(jc * 1280));
      float Kc = bf2f(Kv[jc * 4 + koff]);
      for (int k0 = 0; k0 < deg; k0 += 4) {
        int jn = lnbr[beg + k0 + 4 + g];  // zero-filled tail -> safe
        short8x vn = *(const short8x*)(Yb + (size_t)(unsigned)(jn * 1280));
        float Kn = bf2f(Kv[jn * 4 + koff]);
        float xj[8];
#pragma unroll
        for (int q = 0; q < 8; ++q) xj[q] = bf2f((ushort_t)vj[q]);
        float p = 0.f;
#pragma unroll
        for (int q = 0; q < 8; ++q) {
          float e = xi[q] + xj[q];
          p = fmaf(av[q], __builtin_fabsf(e), p);
        }
        p = dpp_red8(p);  // per-head |z|-dot (lanes 0-7: h0, 8-15: h1)
        float wgt = (k0 + g < deg) ? __builtin_amdgcn_exp2f(p) * Kc : 0.f;
        d += wgt;
#pragma unroll
        for (int q = 0; q < 8; ++q) acc[q] = fmaf(xj[q], wgt, acc[q]);
        vj = vn;
        Kc = Kn;
      }
#pragma unroll
      for (int o = 16; o <= 32; o <<= 1) {  // combine the 4 edge-groups
        d += __shfl_xor(d, o);
#pragma unroll
        for (int q = 0; q < 8; ++q) acc[q] += __shfl_xor(acc[q], o);
      }
    }
    float inv = deg > 0 ? 1.f / d : 0.f;
    float v[8];
#pragma unroll
    for (int q = 0; q < 8; ++q) {
      float tq = acc[q] * inv;
      v[q] = 0.5f * (tq + __shfl_xor(tq, 8));  // mean over heads
    }
    {
      short8x rv = *(const short8x*)(rowp + 512 + (jj & 7) * 16);  // res block
#pragma unroll
      for (int q = 0; q < 8; ++q) v[q] += bf2f((ushort_t)rv[q]);
    }

    if (MODE == 0) {
      float s = 0.f;
#pragma unroll
      for (int q = 0; q < 8; ++q) s += v[q];
      s += __shfl_xor(s, 1);
      s += __shfl_xor(s, 2);
      s += __shfl_xor(s, 4);
      float mu = s * (1.f / 64.f);
      float vs = 0.f;
#pragma unroll
      for (int q = 0; q < 8; ++q) {
        float dv = v[q] - mu;
        vs += dv * dv;
      }
      vs += __shfl_xor(vs, 1);
      vs += __shfl_xor(vs, 2);
      vs += __shfl_xor(vs, 4);
      float rstd = rsqrtf(vs * (1.f / 64.f) + 1e-5f);
      if (g == 0 && jj < 8) {
        const float* lg = dir ? lng1 : lng0;
        const float* lb = dir ? lnb1 : lnb0;
        unsigned o2[8];
#pragma unroll
        for (int q = 0; q < 8; ++q) {
          int c = jj * 8 + q;
          float y = (v[q] - mu) * rstd * lg[c] + lb[c];
          y = fmaxf(y, 0.01f * y);
          o2[q] = f2bf(y);
        }
        uint4 pk;
        pk.x = o2[0] | (o2[1] << 16);
        pk.y = o2[2] | (o2[3] << 16);
        pk.z = o2[4] | (o2[5] << 16);
        pk.w = o2[6] | (o2[7] << 16);
        *(uint4*)((ushort_t*)outp + (size_t)n * 128 + dir * 64 + jj * 8) = pk;
      }
    } else {
      if (g == 0 && jj < 8) {
        float* op = (float*)outp + (size_t)n * 256 + dir * 64 + jj * 8;
        float4 o0, o1;
        o0.x = fmaxf(v[0], 0.01f * v[0]);
        o0.y = fmaxf(v[1], 0.01f * v[1]);
        o0.z = fmaxf(v[2], 0.01f * v[2]);
        o0.w = fmaxf(v[3], 0.01f * v[3]);
        o1.x = fmaxf(v[4], 0.01f * v[4]);
        o1.y = fmaxf(v[5], 0.01f * v[5]);
        o1.z = fmaxf(v[6], 0.01f * v[6]);
        o1.w = fmaxf(v[7], 0.01f * v[7]);
        *(float4*)op = o0;
        *(float4*)(op + 4) = o1;
      }
    }
  }
}

// ---------------------------------------------------------------------------

extern "C" void kernel_launch(void* const* d_in, const int* in_sizes, int n_in,
                              void* d_out, int out_size, void* d_ws, size_t ws_size,
                              hipStream_t stream) {
  const float* x = (const float*)d_in[0];
  const int* ei = (const int*)d_in[1];
  const int N = in_sizes[0] / 128;
  const int E = in_sizes[1] / 2;
  float* out = (float*)d_out;
  const int nbuck = (N + 31) >> 5;
  const int ncoarse = (N + (1 << CSHIFT) - 1) >> CSHIFT;

  char* p = (char*)d_ws;
  auto carve = [&](size_t bytes) {
    char* q = p;
    p += ((bytes + 255) & ~(size_t)255);
    return q;
  };
  int* ctail = (int*)carve(2 * NCMAX * 4);
  int* gc0 = (int*)carve((size_t)ncoarse * CC * 4);
  int* gc1 = (int*)carve((size_t)ncoarse * CC * 4);
  ushort_t* Y1 = (ushort_t*)carve((size_t)N * 640 * 2);
  ushort_t* A2 = (ushort_t*)carve((size_t)N * 128 * 2);
  ushort_t* WT1 = (ushort_t*)carve(640 * 128 * 2);
  ushort_t* WT2 = (ushort_t*)carve(640 * 128 * 2);
  float* bc1 = (float*)carve(640 * 4);
  float* bc2 = (float*)carve(640 * 4);
  float* WS1 = (float*)carve(128 * 4 * 4);
  float* WS2 = (float*)carve(128 * 4 * 4);
  float* sb = (float*)carve(8 * 4);
  ushort_t* K1 = (ushort_t*)carve((size_t)N * 4 * 2);
  ushort_t* K2 = (ushort_t*)carve((size_t)N * 4 * 2);
  int* ctail0 = ctail;
  int* ctail1 = ctail + NCMAX;

  auto F = [&](int i) { return (const float*)d_in[i]; };
  GArgs g1, g2;
  g1.Wl[0] = F(2);  g1.bl[0] = F(3);  g1.Wr[0] = F(4);  g1.br[0] = F(5);
  g1.Wres[0] = F(7); g1.bias[0] = F(8);
  g1.Wl[1] = F(9);  g1.bl[1] = F(10); g1.Wr[1] = F(11); g1.br[1] = F(12);
  g1.Wres[1] = F(14); g1.bias[1] = F(15);
  g2.Wl[0] = F(16); g2.bl[0] = F(17); g2.Wr[0] = F(18); g2.br[0] = F(19);
  g2.Wres[0] = F(21); g2.bias[0] = F(22);
  g2.Wl[1] = F(23); g2.bl[1] = F(24); g2.Wr[1] = F(25); g2.br[1] = F(26);
  g2.Wres[1] = F(28); g2.bias[1] = F(29);

  hipMemsetAsync(ctail, 0, 2 * NCMAX * 4, stream);

  pack_kernel<<<1282, 128, 0, stream>>>(g1, g2, F(6), F(13), F(20), F(27),
                                        WT1, WT2, bc1, bc2, WS1, WS2, sb);

  const int nbinA = (E + EPB - 1) / EPB;
  const int nrow = (N + 63) / 64;
  const int ngemm = nrow * 5;
  const int ncopy = (N * 32 + 255) / 256;
  k_front<<<nbinA + ngemm + ncopy + nrow, 256, 0, stream>>>(
      x, ei, E, N, gc0, gc1, ctail0, ctail1, WT1, bc1, WS1, sb, K1, Y1, out,
      nbinA, ngemm, nrow, ncopy);

  const dim3 ga(nbuck, 2);
  agg_bucket<0><<<ga, 256, 0, stream>>>(Y1, gc0, gc1, ctail0, ctail1, K1,
                                        F(6), F(13), F(30), F(31), F(32), F(33),
                                        A2, N);
  gemm2_kernel<<<dim3(nrow, 6), 256, 0, stream>>>(A2, WT2, bc2, WS2, sb, K2, Y1, N);
  agg_bucket<1><<<ga, 256, 0, stream>>>(Y1, gc0, gc1, ctail0, ctail1, K2,
                                        F(20), F(27), nullptr, nullptr, nullptr,
                                        nullptr, out, N);
}

// Round 12
// 310.758 us; speedup vs baseline: 1.0529x; 1.0529x over previous
//
#include <hip/hip_runtime.h>
#include <math.h>

typedef unsigned short ushort_t;
typedef __attribute__((ext_vector_type(8))) short short8x;
typedef __attribute__((ext_vector_type(4))) float f32x4;
typedef __attribute__((ext_vector_type(2))) float f32x2;

#define CSHIFT 9        // coarse bucket = 512 nodes
#define CC 12288        // entries per coarse bucket (mean ~8163, +45 sigma)
#define EPB 4096        // edges per pass-A block
#define ECAP 1024       // staged entries per fine bucket (mean ~512)
#define NCMAX 128       // max coarse buckets (N<65536 -> <=128)

__device__ __forceinline__ unsigned f2bf(float f) {
  unsigned u = __float_as_uint(f);
  u += 0x7fff + ((u >> 16) & 1);
  return u >> 16;
}
__device__ __forceinline__ float bf2f(ushort_t u) {
  return __uint_as_float(((unsigned)u) << 16);
}
// sum over the 8-lane half of each 16-lane DPP row (pure VALU, no LDS pipe)
__device__ __forceinline__ float dpp_red8(float v) {
  v += __int_as_float(__builtin_amdgcn_update_dpp(0, __float_as_int(v), 0xB1, 0xF, 0xF, true));   // quad_perm xor1
  v += __int_as_float(__builtin_amdgcn_update_dpp(0, __float_as_int(v), 0x4E, 0xF, 0xF, true));   // quad_perm xor2
  v += __int_as_float(__builtin_amdgcn_update_dpp(0, __float_as_int(v), 0x141, 0xF, 0xF, true));  // row_half_mirror
  return v;
}

struct GArgs {
  const float* Wl[2];
  const float* bl[2];
  const float* Wr[2];
  const float* br[2];
  const float* Wres[2];
  const float* bias[2];
};

// identity column layout, col in [0,640): dir=col/320; cc<128: Wl, <256: Wr, else Wres
__device__ __forceinline__ float wval1(const GArgs& ga, int col, int k) {
  int dir = col >= 320 ? 1 : 0;
  int cc = col - dir * 320;
  return cc < 128 ? ga.Wl[dir][k * 128 + cc]
       : cc < 256 ? ga.Wr[dir][k * 128 + (cc - 128)]
                  : ga.Wres[dir][k * 64 + (cc - 256)];
}
__device__ __forceinline__ float bval(const GArgs& ga, int col) {
  int dir = col >= 320 ? 1 : 0;
  int cc = col - dir * 320;
  return cc < 128 ? ga.bl[dir][cc]
       : cc < 256 ? ga.br[dir][cc - 128]
                  : ga.bias[dir][cc - 256];
}

// ------------------------- weight packing ----------------------------------
// WT1[640][128] (full K), WT2[640][128] (block-diag: k<64 -> dir0, k>=64 -> dir1)

__global__ __launch_bounds__(128) void pack_kernel(GArgs g1, GArgs g2,
                                                   ushort_t* __restrict__ WT1,
                                                   ushort_t* __restrict__ WT2,
                                                   float* __restrict__ bc1,
                                                   float* __restrict__ bc2) {
  int b = blockIdx.x;
  int k = threadIdx.x;
  if (b < 640) {
    WT1[b * 128 + k] = (ushort_t)f2bf(wval1(g1, b, k));
  } else if (b < 1280) {
    int c = b - 640;
    int dir = c >= 320 ? 1 : 0;
    int cc = c - dir * 320;
    float v = 0.f;
    if ((k >> 6) == dir) {
      int k2 = k & 63;
      v = cc < 128 ? g2.Wl[dir][k2 * 128 + cc]
        : cc < 256 ? g2.Wr[dir][k2 * 128 + (cc - 128)]
                   : g2.Wres[dir][k2 * 64 + (cc - 256)];
    }
    WT2[c * 128 + k] = (ushort_t)f2bf(v);
  } else {
    for (int c = k; c < 640; c += 128) {
      bc1[c] = bval(g1, c);
      bc2[c] = bval(g2, c);
    }
  }
}

// ------------------------- bf16 MFMA GEMM body -----------------------------
// Y[N][640] = A[N][128] * WT^T + bc.  Block: 64 rows x 128 cols, 4 waves.
// AF32=1: A is f32 (inline cvt to bf16 while staging).

template <int AF32>
__device__ __forceinline__ void gemm_body(const float* Af, const ushort_t* Ab,
                                          const ushort_t* WT, const float* bc,
                                          ushort_t* Y, int N, int rb, int cb,
                                          ushort_t* lds) {
  const int tid = threadIdx.x;
  const int lane = tid & 63;
  const int w = tid >> 6;
  const int m0 = rb * 64;
  const int cbase = cb * 128 + w * 32;

#pragma unroll
  for (int c = 0; c < 4; ++c) {
    int Lb = (tid + c * 256) * 16;
    int row = Lb >> 8, within = Lb & 255;
    int so = within ^ ((row & 7) << 4);
    int grow = m0 + row;
    if (grow >= N) grow = N - 1;
    if (AF32) {
      const float* src = Af + (size_t)grow * 128 + (so >> 1);
      float4 a = *(const float4*)src;
      float4 b = *(const float4*)(src + 4);
      uint4 o;
      o.x = f2bf(a.x) | (f2bf(a.y) << 16);
      o.y = f2bf(a.z) | (f2bf(a.w) << 16);
      o.z = f2bf(b.x) | (f2bf(b.y) << 16);
      o.w = f2bf(b.z) | (f2bf(b.w) << 16);
      ((uint4*)lds)[tid + c * 256] = o;
    } else {
      ((uint4*)lds)[tid + c * 256] = *(const uint4*)(Ab + (size_t)grow * 128 + (so >> 1));
    }
  }

  short8x bf[4][2];
#pragma unroll
  for (int ks = 0; ks < 4; ++ks)
#pragma unroll
    for (int ns = 0; ns < 2; ++ns) {
      int col = cbase + ns * 16 + (lane & 15);
      bf[ks][ns] = *(const short8x*)(WT + (size_t)col * 128 + ks * 32 + (lane >> 4) * 8);
    }

  __syncthreads();

  f32x4 z = {0.f, 0.f, 0.f, 0.f};
  f32x4 acc[4][2];
#pragma unroll
  for (int ms = 0; ms < 4; ++ms) {
    acc[ms][0] = z;
    acc[ms][1] = z;
  }
#pragma unroll
  for (int ks = 0; ks < 4; ++ks) {
    short8x af[4];
#pragma unroll
    for (int ms = 0; ms < 4; ++ms) {
      int row = ms * 16 + (lane & 15);
      int byte = row * 256 + ((ks * 64 + (lane >> 4) * 16) ^ ((row & 7) << 4));
      af[ms] = *(const short8x*)((const char*)lds + byte);
    }
#pragma unroll
    for (int ms = 0; ms < 4; ++ms) {
      acc[ms][0] = __builtin_amdgcn_mfma_f32_16x16x32_bf16(af[ms], bf[ks][0], acc[ms][0], 0, 0, 0);
      acc[ms][1] = __builtin_amdgcn_mfma_f32_16x16x32_bf16(af[ms], bf[ks][1], acc[ms][1], 0, 0, 0);
    }
  }

#pragma unroll
  for (int ms = 0; ms < 4; ++ms)
#pragma unroll
    for (int ns = 0; ns < 2; ++ns) {
      int col = cbase + ns * 16 + (lane & 15);
      float bv = bc[col];
#pragma unroll
      for (int r = 0; r < 4; ++r) {
        int grow = m0 + ms * 16 + (lane >> 4) * 4 + r;
        if (grow < N) Y[(size_t)grow * 640 + col] = (ushort_t)f2bf(acc[ms][ns][r] + bv);
      }
    }
}

// ---------------- fused front-end: coarse-bin | gemm1 | copy_x -------------
// Pass A: radix partition into 512-node coarse buckets. Per block: LDS hist,
// ONE global atomicAdd per (block,bucket), scatter in ~42-entry runs.
// Entry = (nbr<<16)|node (both <2^16).

__global__ __launch_bounds__(256) void k_front(
    const float* __restrict__ x, const int* __restrict__ ei, int E, int N,
    int* __restrict__ gc0, int* __restrict__ gc1, int* __restrict__ ctail0,
    int* __restrict__ ctail1, const ushort_t* __restrict__ WT1,
    const float* __restrict__ bc1, ushort_t* __restrict__ Y,
    float* __restrict__ out, int nbinA, int ngemm, int nrow) {
  __shared__ ushort_t lds[8192];
  const int bid = blockIdx.x;
  const int t = threadIdx.x;
  if (bid < nbinA) {
    int* h0 = (int*)lds;
    int* h1 = h0 + NCMAX;
    int* b0 = h1 + NCMAX;
    int* b1 = b0 + NCMAX;
    const int e0 = bid * EPB;
    const int e1 = min(e0 + EPB, E);
    for (int i = t; i < NCMAX; i += 256) {
      h0[i] = 0;
      h1[i] = 0;
    }
    __syncthreads();
    for (int i = e0 + t; i < e1; i += 256) {
      int s = ei[i], d = ei[E + i];
      atomicAdd(&h0[d >> CSHIFT], 1);
      atomicAdd(&h1[s >> CSHIFT], 1);
    }
    __syncthreads();
    for (int c = t; c < NCMAX; c += 256) {
      int n0 = h0[c], n1 = h1[c];
      b0[c] = n0 ? atomicAdd(&ctail0[c], n0) : 0;
      b1[c] = n1 ? atomicAdd(&ctail1[c], n1) : 0;
      h0[c] = 0;
      h1[c] = 0;
    }
    __syncthreads();
    for (int i = e0 + t; i < e1; i += 256) {
      int s = ei[i], d = ei[E + i];
      int c0 = d >> CSHIFT;
      int p0 = b0[c0] + atomicAdd(&h0[c0], 1);
      if (p0 < CC) gc0[c0 * CC + p0] = (s << 16) | d;
      int c1 = s >> CSHIFT;
      int p1 = b1[c1] + atomicAdd(&h1[c1], 1);
      if (p1 < CC) gc1[c1 * CC + p1] = (d << 16) | s;
    }
  } else if (bid < nbinA + ngemm) {
    int gb = bid - nbinA;
    gemm_body<1>(x, nullptr, WT1, bc1, Y, N, gb % nrow, gb / nrow, lds);
  } else {
    int i = (bid - nbinA - ngemm) * 256 + t;
    if (i < N * 32) {
      float4 v = ((const float4*)x)[i];
      ((float4*)out)[(size_t)(i >> 5) * 64 + 32 + (i & 31)] = v;
    }
  }
}

// ---------------------------- layer-2 GEMM ---------------------------------

__global__ __launch_bounds__(256) void gemm2_kernel(const ushort_t* __restrict__ A,
                                                    const ushort_t* __restrict__ WT,
                                                    const float* __restrict__ bc,
                                                    ushort_t* __restrict__ Y, int N) {
  __shared__ ushort_t lds[8192];
  gemm_body<0>(nullptr, A, WT, bc, Y, N, blockIdx.x, blockIdx.y, lds);
}

// -------- fused aggregation: one block per 32-node fine bucket -------------
// Prologue: stream parent coarse bucket (coalesced, shared by 16 blocks),
// filter into LDS, build local CSR. Inner loop: 16 lanes/edge, 4 edges/wave,
// packed-f32 (VOP3P) channel math, 2-deep row prefetch. lnbr zero-padded so
// all index/gather reads are unconditional (row 0, masked by wgt=0).
// No max subtraction (logits tiny; softmax ratio identical).

template <int MODE>  // 0: L1 (LayerNorm, bf16 out [N][128]), 1: L2 (f32 out [N][256])
__global__ __launch_bounds__(256) void agg_bucket(
    const ushort_t* __restrict__ Y, const int* __restrict__ gc0,
    const int* __restrict__ gc1, const int* __restrict__ ctail0,
    const int* __restrict__ ctail1, const float* __restrict__ attA,
    const float* __restrict__ attB, const float* __restrict__ lng0,
    const float* __restrict__ lnb0, const float* __restrict__ lng1,
    const float* __restrict__ lnb1, void* __restrict__ outp, int N) {
  __shared__ int ebuf[ECAP];
  __shared__ int lnbr[ECAP + 24];  // pre-multiplied row byte offsets + pad
  __shared__ int hist[32], offs[32], cur[32];
  __shared__ int ecnt;
  const int fb = blockIdx.x;
  const int cb = fb >> 4;
  const int dir = blockIdx.y;
  const int t = threadIdx.x;
  const int* gc = dir ? gc1 : gc0;
  const int* ctail = dir ? ctail1 : ctail0;
  const float* att = dir ? attB : attA;

  for (int i = t; i < ECAP + 24; i += 256) lnbr[i] = 0;
  if (t < 32) {
    hist[t] = 0;
    cur[t] = 0;
  }
  if (t == 64) ecnt = 0;
  __syncthreads();

  {
    const int cntc = min(ctail[cb], CC);
    const int* src = gc + cb * CC;
    for (int i = t; i < cntc; i += 256) {
      int e = src[i];
      if (((e & 0xFFFF) >> 5) == fb) {
        int idx = atomicAdd(&ecnt, 1);
        if (idx < ECAP) ebuf[idx] = e;
      }
    }
  }
  __syncthreads();
  const int tot = min(ecnt, ECAP);
  for (int i = t; i < tot; i += 256) atomicAdd(&hist[ebuf[i] & 31], 1);
  __syncthreads();
  if (t < 32) {
    int v = hist[t], inc = v;
#pragma unroll
    for (int o = 1; o < 32; o <<= 1) {
      int u = __shfl_up(inc, o);
      if (t >= o) inc += u;
    }
    offs[t] = inc - v;
  }
  __syncthreads();
  for (int i = t; i < tot; i += 256) {
    int e = ebuf[i];
    int r = e & 31;
    lnbr[offs[r] + atomicAdd(&cur[r], 1)] = (int)((unsigned)e >> 16) * 1280;
  }
  __syncthreads();

  const int wv = t >> 6, lane = t & 63, g = lane >> 4, jj = lane & 15;
  const float L2E = 1.4426950408889634f;
  f32x2 av2[4];
  {
    float4 a0 = *(const float4*)(att + jj * 8);
    float4 a1 = *(const float4*)(att + jj * 8 + 4);
    av2[0] = (f32x2){a0.x * L2E, a0.y * L2E};
    av2[1] = (f32x2){a0.z * L2E, a0.w * L2E};
    av2[2] = (f32x2){a1.x * L2E, a1.y * L2E};
    av2[3] = (f32x2){a1.z * L2E, a1.w * L2E};
  }
  const char* Yb = (const char*)Y + dir * 640 + jj * 16;  // + row byte offset -> xl chans

  for (int r = wv; r < 32; r += 4) {
    const int n = fb * 32 + r;
    if (n >= N) break;
    const char* rowp = (const char*)Y + (size_t)n * 1280 + dir * 640;

    f32x2 xi2[4];
    {
      uint4 v = *(const uint4*)(rowp + 256 + jj * 16);  // xr block
      xi2[0] = (f32x2){__uint_as_float(v.x << 16), __uint_as_float(v.x & 0xffff0000u)};
      xi2[1] = (f32x2){__uint_as_float(v.y << 16), __uint_as_float(v.y & 0xffff0000u)};
      xi2[2] = (f32x2){__uint_as_float(v.z << 16), __uint_as_float(v.z & 0xffff0000u)};
      xi2[3] = (f32x2){__uint_as_float(v.w << 16), __uint_as_float(v.w & 0xffff0000u)};
    }
    float d = 0.f;
    f32x2 acc2[4];
#pragma unroll
    for (int q = 0; q < 4; ++q) acc2[q] = (f32x2){0.f, 0.f};

    const int beg = offs[r], deg = hist[r];
    if (deg > 0) {
      int o0 = lnbr[beg + g];
      int o1 = lnbr[beg + 4 + g];
      uint4 v0 = *(const uint4*)(Yb + (size_t)(unsigned)o0);
      uint4 v1 = *(const uint4*)(Yb + (size_t)(unsigned)o1);
      for (int k0 = 0; k0 < deg; k0 += 4) {
        int o2 = lnbr[beg + k0 + 8 + g];  // zero-filled tail -> safe
        uint4 v2 = *(const uint4*)(Yb + (size_t)(unsigned)o2);
        f32x2 xj2[4];
        xj2[0] = (f32x2){__uint_as_float(v0.x << 16), __uint_as_float(v0.x & 0xffff0000u)};
        xj2[1] = (f32x2){__uint_as_float(v0.y << 16), __uint_as_float(v0.y & 0xffff0000u)};
        xj2[2] = (f32x2){__uint_as_float(v0.z << 16), __uint_as_float(v0.z & 0xffff0000u)};
        xj2[3] = (f32x2){__uint_as_float(v0.w << 16), __uint_as_float(v0.w & 0xffff0000u)};
        f32x2 p2 = (f32x2){0.f, 0.f};
#pragma unroll
        for (int q = 0; q < 4; ++q) {
          f32x2 e2 = xi2[q] + xj2[q];
          f32x2 l2 = __builtin_elementwise_max(e2, e2 * 0.2f);  // leaky-relu
          p2 += l2 * av2[q];
        }
        float p = dpp_red8(p2.x + p2.y);  // per-head logit*log2e
        float wgt = (k0 + g < deg) ? __builtin_amdgcn_exp2f(p) : 0.f;
        d += wgt;
#pragma unroll
        for (int q = 0; q < 4; ++q) acc2[q] += xj2[q] * wgt;
        v0 = v1;
        v1 = v2;
      }
#pragma unroll
      for (int o = 16; o <= 32; o <<= 1) {  // combine the 4 edge-groups
        d += __shfl_xor(d, o);
#pragma unroll
        for (int q = 0; q < 4; ++q) {
          acc2[q].x += __shfl_xor(acc2[q].x, o);
          acc2[q].y += __shfl_xor(acc2[q].y, o);
        }
      }
    }
    float inv = deg > 0 ? 1.f / d : 0.f;
    float v[8];
#pragma unroll
    for (int q = 0; q < 4; ++q) {
      float t0 = acc2[q].x * inv;
      float t1 = acc2[q].y * inv;
      v[2 * q] = 0.5f * (t0 + __shfl_xor(t0, 8));  // mean over heads
      v[2 * q + 1] = 0.5f * (t1 + __shfl_xor(t1, 8));
    }
    {
      short8x rv = *(const short8x*)(rowp + 512 + (jj & 7) * 16);  // res block
#pragma unroll
      for (int q = 0; q < 8; ++q) v[q] += bf2f((ushort_t)rv[q]);
    }

    if (MODE == 0) {
      float s = 0.f;
#pragma unroll
      for (int q = 0; q < 8; ++q) s += v[q];
      s += __shfl_xor(s, 1);
      s += __shfl_xor(s, 2);
      s += __shfl_xor(s, 4);
      float mu = s * (1.f / 64.f);
      float vs = 0.f;
#pragma unroll
      for (int q = 0; q < 8; ++q) {
        float dv = v[q] - mu;
        vs += dv * dv;
      }
      vs += __shfl_xor(vs, 1);
      vs += __shfl_xor(vs, 2);
      vs += __shfl_xor(vs, 4);
      float rstd = rsqrtf(vs * (1.f / 64.f) + 1e-5f);
      if (g == 0 && jj < 8) {
        const float* lg = dir ? lng1 : lng0;
        const float* lb = dir ? lnb1 : lnb0;
        unsigned o2[8];
#pragma unroll
        for (int q = 0; q < 8; ++q) {
          int c = jj * 8 + q;
          float y = (v[q] - mu) * rstd * lg[c] + lb[c];
          y = fmaxf(y, 0.01f * y);
          o2[q] = f2bf(y);
        }
        uint4 pk;
        pk.x = o2[0] | (o2[1] << 16);
        pk.y = o2[2] | (o2[3] << 16);
        pk.z = o2[4] | (o2[5] << 16);
        pk.w = o2[6] | (o2[7] << 16);
        *(uint4*)((ushort_t*)outp + (size_t)n * 128 + dir * 64 + jj * 8) = pk;
      }
    } else {
      if (g == 0 && jj < 8) {
        float* op = (float*)outp + (size_t)n * 256 + dir * 64 + jj * 8;
        float4 o0, o1;
        o0.x = fmaxf(v[0], 0.01f * v[0]);
        o0.y = fmaxf(v[1], 0.01f * v[1]);
        o0.z = fmaxf(v[2], 0.01f * v[2]);
        o0.w = fmaxf(v[3], 0.01f * v[3]);
        o1.x = fmaxf(v[4], 0.01f * v[4]);
        o1.y = fmaxf(v[5], 0.01f * v[5]);
        o1.z = fmaxf(v[6], 0.01f * v[6]);
        o1.w = fmaxf(v[7], 0.01f * v[7]);
        *(float4*)op = o0;
        *(float4*)(op + 4) = o1;
      }
    }
  }
}

// ---------------------------------------------------------------------------

extern "C" void kernel_launch(void* const* d_in, const int* in_sizes, int n_in,
                              void* d_out, int out_size, void* d_ws, size_t ws_size,
                              hipStream_t stream) {
  const float* x = (const float*)d_in[0];
  const int* ei = (const int*)d_in[1];
  const int N = in_sizes[0] / 128;
  const int E = in_sizes[1] / 2;
  float* out = (float*)d_out;
  const int nbuck = (N + 31) >> 5;
  const int ncoarse = (N + (1 << CSHIFT) - 1) >> CSHIFT;

  char* p = (char*)d_ws;
  auto carve = [&](size_t bytes) {
    char* q = p;
    p += ((bytes + 255) & ~(size_t)255);
    return q;
  };
  int* ctail = (int*)carve(2 * NCMAX * 4);
  int* gc0 = (int*)carve((size_t)ncoarse * CC * 4);
  int* gc1 = (int*)carve((size_t)ncoarse * CC * 4);
  ushort_t* Y1 = (ushort_t*)carve((size_t)N * 640 * 2);
  ushort_t* A2 = (ushort_t*)carve((size_t)N * 128 * 2);
  ushort_t* WT1 = (ushort_t*)carve(640 * 128 * 2);
  ushort_t* WT2 = (ushort_t*)carve(640 * 128 * 2);
  float* bc1 = (float*)carve(640 * 4);
  float* bc2 = (float*)carve(640 * 4);
  int* ctail0 = ctail;
  int* ctail1 = ctail + NCMAX;

  auto F = [&](int i) { return (const float*)d_in[i]; };
  GArgs g1, g2;
  g1.Wl[0] = F(2);  g1.bl[0] = F(3);  g1.Wr[0] = F(4);  g1.br[0] = F(5);
  g1.Wres[0] = F(7); g1.bias[0] = F(8);
  g1.Wl[1] = F(9);  g1.bl[1] = F(10); g1.Wr[1] = F(11); g1.br[1] = F(12);
  g1.Wres[1] = F(14); g1.bias[1] = F(15);
  g2.Wl[0] = F(16); g2.bl[0] = F(17); g2.Wr[0] = F(18); g2.br[0] = F(19);
  g2.Wres[0] = F(21); g2.bias[0] = F(22);
  g2.Wl[1] = F(23); g2.bl[1] = F(24); g2.Wr[1] = F(25); g2.br[1] = F(26);
  g2.Wres[1] = F(28); g2.bias[1] = F(29);

  hipMemsetAsync(ctail, 0, 2 * NCMAX * 4, stream);

  pack_kernel<<<1281, 128, 0, stream>>>(g1, g2, WT1, WT2, bc1, bc2);

  const int nbinA = (E + EPB - 1) / EPB;
  const int nrow = (N + 63) / 64;
  const int ngemm = nrow * 5;
  const int ncopy = (N * 32 + 255) / 256;
  k_front<<<nbinA + ngemm + ncopy, 256, 0, stream>>>(
      x, ei, E, N, gc0, gc1, ctail0, ctail1, WT1, bc1, Y1, out,
      nbinA, ngemm, nrow);

  const dim3 ga(nbuck, 2);
  agg_bucket<0><<<ga, 256, 0, stream>>>(Y1, gc0, gc1, ctail0, ctail1, F(6), F(13),
                                        F(30), F(31), F(32), F(33), A2, N);
  gemm2_kernel<<<dim3(nrow, 5), 256, 0, stream>>>(A2, WT2, bc2, Y1, N);
  agg_bucket<1><<<ga, 256, 0, stream>>>(Y1, gc0, gc1, ctail0, ctail1, F(20), F(27),
                                        nullptr, nullptr, nullptr, nullptr, out, N);
}

// Round 13
// 309.816 us; speedup vs baseline: 1.0561x; 1.0030x over previous
//
#include <hip/hip_runtime.h>
#include <math.h>

typedef unsigned short ushort_t;
typedef unsigned char uchar_t;
typedef __attribute__((ext_vector_type(8))) short short8x;
typedef __attribute__((ext_vector_type(4))) float f32x4;
typedef __attribute__((ext_vector_type(2))) float f32x2;

#define CSHIFT 9        // coarse bucket = 512 nodes
#define CC 12288        // entries per coarse bucket (mean ~8163, +45 sigma)
#define EPB 4096        // edges per pass-A block
#define ECAP 1024       // staged entries per fine bucket (mean ~512)
#define NCMAX 128       // max coarse buckets (N<65536 -> <=128)

__device__ __forceinline__ unsigned f2bf(float f) {
  unsigned u = __float_as_uint(f);
  u += 0x7fff + ((u >> 16) & 1);
  return u >> 16;
}
__device__ __forceinline__ float bf2f(ushort_t u) {
  return __uint_as_float(((unsigned)u) << 16);
}
// sum over the 8-lane half of each 16-lane DPP row (pure VALU, no LDS pipe)
__device__ __forceinline__ float dpp_red8(float v) {
  v += __int_as_float(__builtin_amdgcn_update_dpp(0, __float_as_int(v), 0xB1, 0xF, 0xF, true));   // quad_perm xor1
  v += __int_as_float(__builtin_amdgcn_update_dpp(0, __float_as_int(v), 0x4E, 0xF, 0xF, true));   // quad_perm xor2
  v += __int_as_float(__builtin_amdgcn_update_dpp(0, __float_as_int(v), 0x141, 0xF, 0xF, true));  // row_half_mirror
  return v;
}

struct GArgs {
  const float* Wl[2];
  const float* bl[2];
  const float* Wr[2];
  const float* br[2];
  const float* Wres[2];
  const float* bias[2];
};

// identity column layout, col in [0,640): dir=col/320; cc<128: Wl, <256: Wr, else Wres
__device__ __forceinline__ float wval1(const GArgs& ga, int col, int k) {
  int dir = col >= 320 ? 1 : 0;
  int cc = col - dir * 320;
  return cc < 128 ? ga.Wl[dir][k * 128 + cc]
       : cc < 256 ? ga.Wr[dir][k * 128 + (cc - 128)]
                  : ga.Wres[dir][k * 64 + (cc - 256)];
}
__device__ __forceinline__ float bval(const GArgs& ga, int col) {
  int dir = col >= 320 ? 1 : 0;
  int cc = col - dir * 320;
  return cc < 128 ? ga.bl[dir][cc]
       : cc < 256 ? ga.br[dir][cc - 128]
                  : ga.bias[dir][cc - 256];
}

// ------------------------- weight packing ----------------------------------
// WT1[640][128] (full K), WT2[640][128] (block-diag: k<64 -> dir0, k>=64 -> dir1)

__global__ __launch_bounds__(128) void pack_kernel(GArgs g1, GArgs g2,
                                                   ushort_t* __restrict__ WT1,
                                                   ushort_t* __restrict__ WT2,
                                                   float* __restrict__ bc1,
                                                   float* __restrict__ bc2) {
  int b = blockIdx.x;
  int k = threadIdx.x;
  if (b < 640) {
    WT1[b * 128 + k] = (ushort_t)f2bf(wval1(g1, b, k));
  } else if (b < 1280) {
    int c = b - 640;
    int dir = c >= 320 ? 1 : 0;
    int cc = c - dir * 320;
    float v = 0.f;
    if ((k >> 6) == dir) {
      int k2 = k & 63;
      v = cc < 128 ? g2.Wl[dir][k2 * 128 + cc]
        : cc < 256 ? g2.Wr[dir][k2 * 128 + (cc - 128)]
                   : g2.Wres[dir][k2 * 64 + (cc - 256)];
    }
    WT2[c * 128 + k] = (ushort_t)f2bf(v);
  } else {
    for (int c = k; c < 640; c += 128) {
      bc1[c] = bval(g1, c);
      bc2[c] = bval(g2, c);
    }
  }
}

// ------------------------- bf16 MFMA GEMM body -----------------------------
// Y[N][640] = A[N][128] * WT^T + bc.  Block: 64 rows x 128 cols, 4 waves.
// xl columns (cc<128) are written as fp8-e4m3 into XL8[N][2][128]; the rest
// (xr, res) go bf16 into Y. AF32=1: A is f32 (inline cvt while staging).

template <int AF32>
__device__ __forceinline__ void gemm_body(const float* Af, const ushort_t* Ab,
                                          const ushort_t* WT, const float* bc,
                                          ushort_t* Y, uchar_t* XL8, int N,
                                          int rb, int cb, ushort_t* lds) {
  const int tid = threadIdx.x;
  const int lane = tid & 63;
  const int w = tid >> 6;
  const int m0 = rb * 64;
  const int cbase = cb * 128 + w * 32;

#pragma unroll
  for (int c = 0; c < 4; ++c) {
    int Lb = (tid + c * 256) * 16;
    int row = Lb >> 8, within = Lb & 255;
    int so = within ^ ((row & 7) << 4);
    int grow = m0 + row;
    if (grow >= N) grow = N - 1;
    if (AF32) {
      const float* src = Af + (size_t)grow * 128 + (so >> 1);
      float4 a = *(const float4*)src;
      float4 b = *(const float4*)(src + 4);
      uint4 o;
      o.x = f2bf(a.x) | (f2bf(a.y) << 16);
      o.y = f2bf(a.z) | (f2bf(a.w) << 16);
      o.z = f2bf(b.x) | (f2bf(b.y) << 16);
      o.w = f2bf(b.z) | (f2bf(b.w) << 16);
      ((uint4*)lds)[tid + c * 256] = o;
    } else {
      ((uint4*)lds)[tid + c * 256] = *(const uint4*)(Ab + (size_t)grow * 128 + (so >> 1));
    }
  }

  short8x bf[4][2];
#pragma unroll
  for (int ks = 0; ks < 4; ++ks)
#pragma unroll
    for (int ns = 0; ns < 2; ++ns) {
      int col = cbase + ns * 16 + (lane & 15);
      bf[ks][ns] = *(const short8x*)(WT + (size_t)col * 128 + ks * 32 + (lane >> 4) * 8);
    }

  __syncthreads();

  f32x4 z = {0.f, 0.f, 0.f, 0.f};
  f32x4 acc[4][2];
#pragma unroll
  for (int ms = 0; ms < 4; ++ms) {
    acc[ms][0] = z;
    acc[ms][1] = z;
  }
#pragma unroll
  for (int ks = 0; ks < 4; ++ks) {
    short8x af[4];
#pragma unroll
    for (int ms = 0; ms < 4; ++ms) {
      int row = ms * 16 + (lane & 15);
      int byte = row * 256 + ((ks * 64 + (lane >> 4) * 16) ^ ((row & 7) << 4));
      af[ms] = *(const short8x*)((const char*)lds + byte);
    }
#pragma unroll
    for (int ms = 0; ms < 4; ++ms) {
      acc[ms][0] = __builtin_amdgcn_mfma_f32_16x16x32_bf16(af[ms], bf[ks][0], acc[ms][0], 0, 0, 0);
      acc[ms][1] = __builtin_amdgcn_mfma_f32_16x16x32_bf16(af[ms], bf[ks][1], acc[ms][1], 0, 0, 0);
    }
  }

#pragma unroll
  for (int ms = 0; ms < 4; ++ms)
#pragma unroll
    for (int ns = 0; ns < 2; ++ns) {
      int col = cbase + ns * 16 + (lane & 15);
      float bv = bc[col];
      int dir = col >= 320 ? 1 : 0;
      int cc = col - dir * 320;
#pragma unroll
      for (int r = 0; r < 4; ++r) {
        int grow = m0 + ms * 16 + (lane >> 4) * 4 + r;
        if (grow < N) {
          float val = acc[ms][ns][r] + bv;
          if (cc < 128) {
            int pk = __builtin_amdgcn_cvt_pk_fp8_f32(val, val, 0, false);
            XL8[(size_t)grow * 256 + dir * 128 + cc] = (uchar_t)(pk & 0xff);
          } else {
            Y[(size_t)grow * 640 + col] = (ushort_t)f2bf(val);
          }
        }
      }
    }
}

// ---------------- fused front-end: coarse-bin | gemm1 | copy_x -------------
// Pass A: radix partition into 512-node coarse buckets. Per block: LDS hist,
// ONE global atomicAdd per (block,bucket), scatter in ~42-entry runs.
// Entry = (nbr<<16)|node (both <2^16).

__global__ __launch_bounds__(256) void k_front(
    const float* __restrict__ x, const int* __restrict__ ei, int E, int N,
    int* __restrict__ gc0, int* __restrict__ gc1, int* __restrict__ ctail0,
    int* __restrict__ ctail1, const ushort_t* __restrict__ WT1,
    const float* __restrict__ bc1, ushort_t* __restrict__ Y,
    uchar_t* __restrict__ XL8, float* __restrict__ out, int nbinA, int ngemm,
    int nrow) {
  __shared__ ushort_t lds[8192];
  const int bid = blockIdx.x;
  const int t = threadIdx.x;
  if (bid < nbinA) {
    int* h0 = (int*)lds;
    int* h1 = h0 + NCMAX;
    int* b0 = h1 + NCMAX;
    int* b1 = b0 + NCMAX;
    const int e0 = bid * EPB;
    const int e1 = min(e0 + EPB, E);
    for (int i = t; i < NCMAX; i += 256) {
      h0[i] = 0;
      h1[i] = 0;
    }
    __syncthreads();
    for (int i = e0 + t; i < e1; i += 256) {
      int s = ei[i], d = ei[E + i];
      atomicAdd(&h0[d >> CSHIFT], 1);
      atomicAdd(&h1[s >> CSHIFT], 1);
    }
    __syncthreads();
    for (int c = t; c < NCMAX; c += 256) {
      int n0 = h0[c], n1 = h1[c];
      b0[c] = n0 ? atomicAdd(&ctail0[c], n0) : 0;
      b1[c] = n1 ? atomicAdd(&ctail1[c], n1) : 0;
      h0[c] = 0;
      h1[c] = 0;
    }
    __syncthreads();
    for (int i = e0 + t; i < e1; i += 256) {
      int s = ei[i], d = ei[E + i];
      int c0 = d >> CSHIFT;
      int p0 = b0[c0] + atomicAdd(&h0[c0], 1);
      if (p0 < CC) gc0[c0 * CC + p0] = (s << 16) | d;
      int c1 = s >> CSHIFT;
      int p1 = b1[c1] + atomicAdd(&h1[c1], 1);
      if (p1 < CC) gc1[c1 * CC + p1] = (d << 16) | s;
    }
  } else if (bid < nbinA + ngemm) {
    int gb = bid - nbinA;
    gemm_body<1>(x, nullptr, WT1, bc1, Y, XL8, N, gb % nrow, gb / nrow, lds);
  } else {
    int i = (bid - nbinA - ngemm) * 256 + t;
    if (i < N * 32) {
      float4 v = ((const float4*)x)[i];
      ((float4*)out)[(size_t)(i >> 5) * 64 + 32 + (i & 31)] = v;
    }
  }
}

// ---------------------------- layer-2 GEMM ---------------------------------

__global__ __launch_bounds__(256) void gemm2_kernel(const ushort_t* __restrict__ A,
                                                    const ushort_t* __restrict__ WT,
                                                    const float* __restrict__ bc,
                                                    ushort_t* __restrict__ Y,
                                                    uchar_t* __restrict__ XL8, int N) {
  __shared__ ushort_t lds[8192];
  gemm_body<0>(nullptr, A, WT, bc, Y, XL8, N, blockIdx.x, blockIdx.y, lds);
}

// -------- fused aggregation: one block per 32-node fine bucket -------------
// Prologue: stream parent coarse bucket (coalesced, shared by 16 blocks),
// ballot-compact matching entries into LDS, build local CSR. Inner loop:
// 16 lanes/edge, 4 edges/wave; xj gathered as 8B fp8-e4m3 (HW cvt decode);
// 1-deep prefetch; lnbr zero-padded so reads are unconditional & safe.
// No max subtraction (logits tiny; softmax ratio identical).

template <int MODE>  // 0: L1 (LayerNorm, bf16 out [N][128]), 1: L2 (f32 out [N][256])
__global__ __launch_bounds__(256) void agg_bucket(
    const ushort_t* __restrict__ Y, const uchar_t* __restrict__ XL8,
    const int* __restrict__ gc0, const int* __restrict__ gc1,
    const int* __restrict__ ctail0, const int* __restrict__ ctail1,
    const float* __restrict__ attA, const float* __restrict__ attB,
    const float* __restrict__ lng0, const float* __restrict__ lnb0,
    const float* __restrict__ lng1, const float* __restrict__ lnb1,
    void* __restrict__ outp, int N) {
  __shared__ int ebuf[ECAP];
  __shared__ int lnbr[ECAP + 8];  // pre-multiplied XL8 row byte offsets + pad
  __shared__ int hist[32], offs[32], cur[32];
  __shared__ int ecnt;
  const int fb = blockIdx.x;
  const int cb = fb >> 4;
  const int dir = blockIdx.y;
  const int t = threadIdx.x;
  const int* gc = dir ? gc1 : gc0;
  const int* ctail = dir ? ctail1 : ctail0;
  const float* att = dir ? attB : attA;

  for (int i = t; i < ECAP + 8; i += 256) lnbr[i] = 0;
  if (t < 32) {
    hist[t] = 0;
    cur[t] = 0;
  }
  if (t == 64) ecnt = 0;
  __syncthreads();

  // ballot-compacted filter: 1 LDS atomic per wave-iteration
  {
    const int cntc = min(ctail[cb], CC);
    const int* src = gc + cb * CC;
    const int iters = (cntc + 255) >> 8;
    for (int it = 0; it < iters; ++it) {
      int i = it * 256 + t;
      int e = 0;
      bool m = false;
      if (i < cntc) {
        e = src[i];
        m = ((e & 0xFFFF) >> 5) == fb;
      }
      unsigned long long mk = __ballot(m);
      int cnt = __popcll(mk);
      int base = 0;
      if ((t & 63) == 0 && cnt) base = atomicAdd(&ecnt, cnt);
      base = __shfl(base, 0);
      if (m) {
        int pos = base + __popcll(mk & ((1ull << (t & 63)) - 1));
        if (pos < ECAP) ebuf[pos] = e;
      }
    }
  }
  __syncthreads();
  const int tot = min(ecnt, ECAP);
  for (int i = t; i < tot; i += 256) atomicAdd(&hist[ebuf[i] & 31], 1);
  __syncthreads();
  if (t < 32) {
    int v = hist[t], inc = v;
#pragma unroll
    for (int o = 1; o < 32; o <<= 1) {
      int u = __shfl_up(inc, o);
      if (t >= o) inc += u;
    }
    offs[t] = inc - v;
  }
  __syncthreads();
  for (int i = t; i < tot; i += 256) {
    int e = ebuf[i];
    int r = e & 31;
    lnbr[offs[r] + atomicAdd(&cur[r], 1)] = (int)((unsigned)e >> 16) * 256;
  }
  __syncthreads();

  const int wv = t >> 6, lane = t & 63, g = lane >> 4, jj = lane & 15;
  const float L2E = 1.4426950408889634f;
  float av[8];
  {
    float4 a0 = *(const float4*)(att + jj * 8);
    float4 a1 = *(const float4*)(att + jj * 8 + 4);
    av[0] = a0.x * L2E; av[1] = a0.y * L2E; av[2] = a0.z * L2E; av[3] = a0.w * L2E;
    av[4] = a1.x * L2E; av[5] = a1.y * L2E; av[6] = a1.z * L2E; av[7] = a1.w * L2E;
  }
  const uchar_t* X8b = XL8 + dir * 128 + jj * 8;  // + row byte offset

  for (int r = wv; r < 32; r += 4) {
    const int n = fb * 32 + r;
    if (n >= N) break;
    const char* rowp = (const char*)Y + (size_t)n * 1280 + dir * 640;

    float xi[8];
    {
      short8x v = *(const short8x*)(rowp + 256 + jj * 16);  // xr block (bf16)
#pragma unroll
      for (int q = 0; q < 8; ++q) xi[q] = bf2f((ushort_t)v[q]);
    }
    float d = 0.f;
    float acc[8];
#pragma unroll
    for (int q = 0; q < 8; ++q) acc[q] = 0.f;

    const int beg = offs[r], deg = hist[r];
    if (deg > 0) {
      int off = lnbr[beg + g];
      uint2 v8 = *(const uint2*)(X8b + (size_t)(unsigned)off);
      for (int k0 = 0; k0 < deg; k0 += 4) {
        int offn = lnbr[beg + k0 + 4 + g];  // zero-filled tail -> safe
        uint2 vn = *(const uint2*)(X8b + (size_t)(unsigned)offn);
        f32x2 x01 = __builtin_amdgcn_cvt_pk_f32_fp8((int)v8.x, false);
        f32x2 x23 = __builtin_amdgcn_cvt_pk_f32_fp8((int)v8.x, true);
        f32x2 x45 = __builtin_amdgcn_cvt_pk_f32_fp8((int)v8.y, false);
        f32x2 x67 = __builtin_amdgcn_cvt_pk_f32_fp8((int)v8.y, true);
        float xj[8] = {x01[0], x01[1], x23[0], x23[1],
                       x45[0], x45[1], x67[0], x67[1]};
        float p = 0.f;
#pragma unroll
        for (int q = 0; q < 8; ++q) {
          float e = xi[q] + xj[q];
          e = fmaxf(e, 0.2f * e);  // leaky-relu(0.2), slope > 0
          p = fmaf(e, av[q], p);
        }
        p = dpp_red8(p);  // per-head logit*log2e (lanes 0-7: h0, 8-15: h1)
        float wgt = (k0 + g < deg) ? __builtin_amdgcn_exp2f(p) : 0.f;
        d += wgt;
#pragma unroll
        for (int q = 0; q < 8; ++q) acc[q] = fmaf(xj[q], wgt, acc[q]);
        v8 = vn;
      }
#pragma unroll
      for (int o = 16; o <= 32; o <<= 1) {  // combine the 4 edge-groups
        d += __shfl_xor(d, o);
#pragma unroll
        for (int q = 0; q < 8; ++q) acc[q] += __shfl_xor(acc[q], o);
      }
    }
    float inv = deg > 0 ? 1.f / d : 0.f;
    float v[8];
#pragma unroll
    for (int q = 0; q < 8; ++q) {
      float tq = acc[q] * inv;
      v[q] = 0.5f * (tq + __shfl_xor(tq, 8));  // mean over heads
    }
    {
      short8x rv = *(const short8x*)(rowp + 512 + (jj & 7) * 16);  // res block
#pragma unroll
      for (int q = 0; q < 8; ++q) v[q] += bf2f((ushort_t)rv[q]);
    }

    if (MODE == 0) {
      float s = 0.f;
#pragma unroll
      for (int q = 0; q < 8; ++q) s += v[q];
      s += __shfl_xor(s, 1);
      s += __shfl_xor(s, 2);
      s += __shfl_xor(s, 4);
      float mu = s * (1.f / 64.f);
      float vs = 0.f;
#pragma unroll
      for (int q = 0; q < 8; ++q) {
        float dv = v[q] - mu;
        vs += dv * dv;
      }
      vs += __shfl_xor(vs, 1);
      vs += __shfl_xor(vs, 2);
      vs += __shfl_xor(vs, 4);
      float rstd = rsqrtf(vs * (1.f / 64.f) + 1e-5f);
      if (g == 0 && jj < 8) {
        const float* lg = dir ? lng1 : lng0;
        const float* lb = dir ? lnb1 : lnb0;
        unsigned o2[8];
#pragma unroll
        for (int q = 0; q < 8; ++q) {
          int c = jj * 8 + q;
          float y = (v[q] - mu) * rstd * lg[c] + lb[c];
          y = fmaxf(y, 0.01f * y);
          o2[q] = f2bf(y);
        }
        uint4 pk;
        pk.x = o2[0] | (o2[1] << 16);
        pk.y = o2[2] | (o2[3] << 16);
        pk.z = o2[4] | (o2[5] << 16);
        pk.w = o2[6] | (o2[7] << 16);
        *(uint4*)((ushort_t*)outp + (size_t)n * 128 + dir * 64 + jj * 8) = pk;
      }
    } else {
      if (g == 0 && jj < 8) {
        float* op = (float*)outp + (size_t)n * 256 + dir * 64 + jj * 8;
        float4 o0, o1;
        o0.x = fmaxf(v[0], 0.01f * v[0]);
        o0.y = fmaxf(v[1], 0.01f * v[1]);
        o0.z = fmaxf(v[2], 0.01f * v[2]);
        o0.w = fmaxf(v[3], 0.01f * v[3]);
        o1.x = fmaxf(v[4], 0.01f * v[4]);
        o1.y = fmaxf(v[5], 0.01f * v[5]);
        o1.z = fmaxf(v[6], 0.01f * v[6]);
        o1.w = fmaxf(v[7], 0.01f * v[7]);
        *(float4*)op = o0;
        *(float4*)(op + 4) = o1;
      }
    }
  }
}

// ---------------------------------------------------------------------------

extern "C" void kernel_launch(void* const* d_in, const int* in_sizes, int n_in,
                              void* d_out, int out_size, void* d_ws, size_t ws_size,
                              hipStream_t stream) {
  const float* x = (const float*)d_in[0];
  const int* ei = (const int*)d_in[1];
  const int N = in_sizes[0] / 128;
  const int E = in_sizes[1] / 2;
  float* out = (float*)d_out;
  const int nbuck = (N + 31) >> 5;
  const int ncoarse = (N + (1 << CSHIFT) - 1) >> CSHIFT;

  char* p = (char*)d_ws;
  auto carve = [&](size_t bytes) {
    char* q = p;
    p += ((bytes + 255) & ~(size_t)255);
    return q;
  };
  int* ctail = (int*)carve(2 * NCMAX * 4);
  int* gc0 = (int*)carve((size_t)ncoarse * CC * 4);
  int* gc1 = (int*)carve((size_t)ncoarse * CC * 4);
  ushort_t* Y1 = (ushort_t*)carve((size_t)N * 640 * 2);
  uchar_t* XL8 = (uchar_t*)carve((size_t)N * 256);
  ushort_t* A2 = (ushort_t*)carve((size_t)N * 128 * 2);
  ushort_t* WT1 = (ushort_t*)carve(640 * 128 * 2);
  ushort_t* WT2 = (ushort_t*)carve(640 * 128 * 2);
  float* bc1 = (float*)carve(640 * 4);
  float* bc2 = (float*)carve(640 * 4);
  int* ctail0 = ctail;
  int* ctail1 = ctail + NCMAX;

  auto F = [&](int i) { return (const float*)d_in[i]; };
  GArgs g1, g2;
  g1.Wl[0] = F(2);  g1.bl[0] = F(3);  g1.Wr[0] = F(4);  g1.br[0] = F(5);
  g1.Wres[0] = F(7); g1.bias[0] = F(8);
  g1.Wl[1] = F(9);  g1.bl[1] = F(10); g1.Wr[1] = F(11); g1.br[1] = F(12);
  g1.Wres[1] = F(14); g1.bias[1] = F(15);
  g2.Wl[0] = F(16); g2.bl[0] = F(17); g2.Wr[0] = F(18); g2.br[0] = F(19);
  g2.Wres[0] = F(21); g2.bias[0] = F(22);
  g2.Wl[1] = F(23); g2.bl[1] = F(24); g2.Wr[1] = F(25); g2.br[1] = F(26);
  g2.Wres[1] = F(28); g2.bias[1] = F(29);

  hipMemsetAsync(ctail, 0, 2 * NCMAX * 4, stream);

  pack_kernel<<<1281, 128, 0, stream>>>(g1, g2, WT1, WT2, bc1, bc2);

  const int nbinA = (E + EPB - 1) / EPB;
  const int nrow = (N + 63) / 64;
  const int ngemm = nrow * 5;
  const int ncopy = (N * 32 + 255) / 256;
  k_front<<<nbinA + ngemm + ncopy, 256, 0, stream>>>(
      x, ei, E, N, gc0, gc1, ctail0, ctail1, WT1, bc1, Y1, XL8, out,
      nbinA, ngemm, nrow);

  const dim3 ga(nbuck, 2);
  agg_bucket<0><<<ga, 256, 0, stream>>>(Y1, XL8, gc0, gc1, ctail0, ctail1,
                                        F(6), F(13), F(30), F(31), F(32), F(33),
                                        A2, N);
  gemm2_kernel<<<dim3(nrow, 5), 256, 0, stream>>>(A2, WT2, bc2, Y1, XL8, N);
  agg_bucket<1><<<ga, 256, 0, stream>>>(Y1, XL8, gc0, gc1, ctail0, ctail1,
                                        F(20), F(27), nullptr, nullptr, nullptr,
                                        nullptr, out, N);
}

// Round 14
// 303.720 us; speedup vs baseline: 1.0773x; 1.0201x over previous
//
#include <hip/hip_runtime.h>
#include <math.h>

typedef unsigned short ushort_t;
typedef unsigned char uchar_t;
typedef __attribute__((ext_vector_type(8))) short short8x;
typedef __attribute__((ext_vector_type(4))) float f32x4;
typedef __attribute__((ext_vector_type(2))) float f32x2;

#define CSHIFT 9        // coarse bucket = 512 nodes
#define CC 12288        // entries per coarse bucket (mean ~8163, +45 sigma)
#define EPB 4096        // edges per pass-A block
#define ECAP 2048       // staged entries per 64-node fine bucket (mean ~1024)
#define NCMAX 128       // max coarse buckets (N<65536 -> <=128)

__device__ __forceinline__ unsigned f2bf(float f) {
  unsigned u = __float_as_uint(f);
  u += 0x7fff + ((u >> 16) & 1);
  return u >> 16;
}
__device__ __forceinline__ float bf2f(ushort_t u) {
  return __uint_as_float(((unsigned)u) << 16);
}
// sum over the 8-lane half of each 16-lane DPP row (pure VALU, no LDS pipe)
__device__ __forceinline__ float dpp_red8(float v) {
  v += __int_as_float(__builtin_amdgcn_update_dpp(0, __float_as_int(v), 0xB1, 0xF, 0xF, true));   // quad_perm xor1
  v += __int_as_float(__builtin_amdgcn_update_dpp(0, __float_as_int(v), 0x4E, 0xF, 0xF, true));   // quad_perm xor2
  v += __int_as_float(__builtin_amdgcn_update_dpp(0, __float_as_int(v), 0x141, 0xF, 0xF, true));  // row_half_mirror
  return v;
}

struct GArgs {
  const float* Wl[2];
  const float* bl[2];
  const float* Wr[2];
  const float* br[2];
  const float* Wres[2];
  const float* bias[2];
};

// identity column layout, col in [0,640): dir=col/320; cc<128: Wl, <256: Wr, else Wres
__device__ __forceinline__ float wval1(const GArgs& ga, int col, int k) {
  int dir = col >= 320 ? 1 : 0;
  int cc = col - dir * 320;
  return cc < 128 ? ga.Wl[dir][k * 128 + cc]
       : cc < 256 ? ga.Wr[dir][k * 128 + (cc - 128)]
                  : ga.Wres[dir][k * 64 + (cc - 256)];
}
__device__ __forceinline__ float bval(const GArgs& ga, int col) {
  int dir = col >= 320 ? 1 : 0;
  int cc = col - dir * 320;
  return cc < 128 ? ga.bl[dir][cc]
       : cc < 256 ? ga.br[dir][cc - 128]
                  : ga.bias[dir][cc - 256];
}

// ------------------------- weight packing ----------------------------------
// WT1[640][128] (full K), WT2[640][128] (block-diag: k<64 -> dir0, k>=64 -> dir1)

__global__ __launch_bounds__(128) void pack_kernel(GArgs g1, GArgs g2,
                                                   ushort_t* __restrict__ WT1,
                                                   ushort_t* __restrict__ WT2,
                                                   float* __restrict__ bc1,
                                                   float* __restrict__ bc2) {
  int b = blockIdx.x;
  int k = threadIdx.x;
  if (b < 640) {
    WT1[b * 128 + k] = (ushort_t)f2bf(wval1(g1, b, k));
  } else if (b < 1280) {
    int c = b - 640;
    int dir = c >= 320 ? 1 : 0;
    int cc = c - dir * 320;
    float v = 0.f;
    if ((k >> 6) == dir) {
      int k2 = k & 63;
      v = cc < 128 ? g2.Wl[dir][k2 * 128 + cc]
        : cc < 256 ? g2.Wr[dir][k2 * 128 + (cc - 128)]
                   : g2.Wres[dir][k2 * 64 + (cc - 256)];
    }
    WT2[c * 128 + k] = (ushort_t)f2bf(v);
  } else {
    for (int c = k; c < 640; c += 128) {
      bc1[c] = bval(g1, c);
      bc2[c] = bval(g2, c);
    }
  }
}

// ------------------------- bf16 MFMA GEMM body -----------------------------
// Y[N][640] = A[N][128] * WT^T + bc.  Block: 64 rows x 128 cols, 4 waves.
// xl columns (cc<128) are written as fp8-e4m3 into XL8[N][2][128]; the rest
// (xr, res) go bf16 into Y. AF32=1: A is f32 (inline cvt while staging).

template <int AF32>
__device__ __forceinline__ void gemm_body(const float* Af, const ushort_t* Ab,
                                          const ushort_t* WT, const float* bc,
                                          ushort_t* Y, uchar_t* XL8, int N,
                                          int rb, int cb, ushort_t* lds) {
  const int tid = threadIdx.x;
  const int lane = tid & 63;
  const int w = tid >> 6;
  const int m0 = rb * 64;
  const int cbase = cb * 128 + w * 32;

#pragma unroll
  for (int c = 0; c < 4; ++c) {
    int Lb = (tid + c * 256) * 16;
    int row = Lb >> 8, within = Lb & 255;
    int so = within ^ ((row & 7) << 4);
    int grow = m0 + row;
    if (grow >= N) grow = N - 1;
    if (AF32) {
      const float* src = Af + (size_t)grow * 128 + (so >> 1);
      float4 a = *(const float4*)src;
      float4 b = *(const float4*)(src + 4);
      uint4 o;
      o.x = f2bf(a.x) | (f2bf(a.y) << 16);
      o.y = f2bf(a.z) | (f2bf(a.w) << 16);
      o.z = f2bf(b.x) | (f2bf(b.y) << 16);
      o.w = f2bf(b.z) | (f2bf(b.w) << 16);
      ((uint4*)lds)[tid + c * 256] = o;
    } else {
      ((uint4*)lds)[tid + c * 256] = *(const uint4*)(Ab + (size_t)grow * 128 + (so >> 1));
    }
  }

  short8x bf[4][2];
#pragma unroll
  for (int ks = 0; ks < 4; ++ks)
#pragma unroll
    for (int ns = 0; ns < 2; ++ns) {
      int col = cbase + ns * 16 + (lane & 15);
      bf[ks][ns] = *(const short8x*)(WT + (size_t)col * 128 + ks * 32 + (lane >> 4) * 8);
    }

  __syncthreads();

  f32x4 z = {0.f, 0.f, 0.f, 0.f};
  f32x4 acc[4][2];
#pragma unroll
  for (int ms = 0; ms < 4; ++ms) {
    acc[ms][0] = z;
    acc[ms][1] = z;
  }
#pragma unroll
  for (int ks = 0; ks < 4; ++ks) {
    short8x af[4];
#pragma unroll
    for (int ms = 0; ms < 4; ++ms) {
      int row = ms * 16 + (lane & 15);
      int byte = row * 256 + ((ks * 64 + (lane >> 4) * 16) ^ ((row & 7) << 4));
      af[ms] = *(const short8x*)((const char*)lds + byte);
    }
#pragma unroll
    for (int ms = 0; ms < 4; ++ms) {
      acc[ms][0] = __builtin_amdgcn_mfma_f32_16x16x32_bf16(af[ms], bf[ks][0], acc[ms][0], 0, 0, 0);
      acc[ms][1] = __builtin_amdgcn_mfma_f32_16x16x32_bf16(af[ms], bf[ks][1], acc[ms][1], 0, 0, 0);
    }
  }

#pragma unroll
  for (int ms = 0; ms < 4; ++ms)
#pragma unroll
    for (int ns = 0; ns < 2; ++ns) {
      int col = cbase + ns * 16 + (lane & 15);
      float bv = bc[col];
      int dir = col >= 320 ? 1 : 0;
      int cc = col - dir * 320;
#pragma unroll
      for (int r = 0; r < 4; ++r) {
        int grow = m0 + ms * 16 + (lane >> 4) * 4 + r;
        if (grow < N) {
          float val = acc[ms][ns][r] + bv;
          if (cc < 128) {
            int pk = __builtin_amdgcn_cvt_pk_fp8_f32(val, val, 0, false);
            XL8[(size_t)grow * 256 + dir * 128 + cc] = (uchar_t)(pk & 0xff);
          } else {
            Y[(size_t)grow * 640 + col] = (ushort_t)f2bf(val);
          }
        }
      }
    }
}

// ---------------- fused front-end: coarse-bin | gemm1 | copy_x -------------

__global__ __launch_bounds__(256) void k_front(
    const float* __restrict__ x, const int* __restrict__ ei, int E, int N,
    int* __restrict__ gc0, int* __restrict__ gc1, int* __restrict__ ctail0,
    int* __restrict__ ctail1, const ushort_t* __restrict__ WT1,
    const float* __restrict__ bc1, ushort_t* __restrict__ Y,
    uchar_t* __restrict__ XL8, float* __restrict__ out, int nbinA, int ngemm,
    int nrow) {
  __shared__ ushort_t lds[8192];
  const int bid = blockIdx.x;
  const int t = threadIdx.x;
  if (bid < nbinA) {
    int* h0 = (int*)lds;
    int* h1 = h0 + NCMAX;
    int* b0 = h1 + NCMAX;
    int* b1 = b0 + NCMAX;
    const int e0 = bid * EPB;
    const int e1 = min(e0 + EPB, E);
    for (int i = t; i < NCMAX; i += 256) {
      h0[i] = 0;
      h1[i] = 0;
    }
    __syncthreads();
    for (int i = e0 + t; i < e1; i += 256) {
      int s = ei[i], d = ei[E + i];
      atomicAdd(&h0[d >> CSHIFT], 1);
      atomicAdd(&h1[s >> CSHIFT], 1);
    }
    __syncthreads();
    for (int c = t; c < NCMAX; c += 256) {
      int n0 = h0[c], n1 = h1[c];
      b0[c] = n0 ? atomicAdd(&ctail0[c], n0) : 0;
      b1[c] = n1 ? atomicAdd(&ctail1[c], n1) : 0;
      h0[c] = 0;
      h1[c] = 0;
    }
    __syncthreads();
    for (int i = e0 + t; i < e1; i += 256) {
      int s = ei[i], d = ei[E + i];
      int c0 = d >> CSHIFT;
      int p0 = b0[c0] + atomicAdd(&h0[c0], 1);
      if (p0 < CC) gc0[c0 * CC + p0] = (s << 16) | d;
      int c1 = s >> CSHIFT;
      int p1 = b1[c1] + atomicAdd(&h1[c1], 1);
      if (p1 < CC) gc1[c1 * CC + p1] = (d << 16) | s;
    }
  } else if (bid < nbinA + ngemm) {
    int gb = bid - nbinA;
    gemm_body<1>(x, nullptr, WT1, bc1, Y, XL8, N, gb % nrow, gb / nrow, lds);
  } else {
    int i = (bid - nbinA - ngemm) * 256 + t;
    if (i < N * 32) {
      float4 v = ((const float4*)x)[i];
      ((float4*)out)[(size_t)(i >> 5) * 64 + 32 + (i & 31)] = v;
    }
  }
}

// ---------------------------- layer-2 GEMM ---------------------------------

__global__ __launch_bounds__(256) void gemm2_kernel(const ushort_t* __restrict__ A,
                                                    const ushort_t* __restrict__ WT,
                                                    const float* __restrict__ bc,
                                                    ushort_t* __restrict__ Y,
                                                    uchar_t* __restrict__ XL8, int N) {
  __shared__ ushort_t lds[8192];
  gemm_body<0>(nullptr, A, WT, bc, Y, XL8, N, blockIdx.x, blockIdx.y, lds);
}

// -------- fused aggregation: one block per 64-node fine bucket -------------
// XCD-aware decode: all 8 sibling blocks of a coarse bucket land on the same
// XCD (bid%8), so the coarse-bucket stream is fetched into that XCD's L2 once.
// Prologue: ballot-compact matching entries into LDS, build local CSR.
// Inner loop: 16 lanes/edge, 4 edges/wave; xj gathered as 8B fp8-e4m3
// (HW cvt decode); 2-deep row prefetch; lnbr zero-padded so all reads are
// unconditional & safe. No max subtraction (logits tiny; ratio identical).

template <int MODE>  // 0: L1 (LayerNorm, bf16 out [N][128]), 1: L2 (f32 out [N][256])
__global__ __launch_bounds__(256) void agg_bucket(
    const ushort_t* __restrict__ Y, const uchar_t* __restrict__ XL8,
    const int* __restrict__ gc0, const int* __restrict__ gc1,
    const int* __restrict__ ctail0, const int* __restrict__ ctail1,
    const float* __restrict__ attA, const float* __restrict__ attB,
    const float* __restrict__ lng0, const float* __restrict__ lnb0,
    const float* __restrict__ lng1, const float* __restrict__ lnb1,
    void* __restrict__ outp, int ncoarse, int N) {
  __shared__ int ebuf[ECAP];
  __shared__ int lnbr[ECAP + 24];  // pre-multiplied XL8 row byte offsets + pad
  __shared__ int hist[64], offs[64], cur[64];
  __shared__ int ecnt;
  const int bid = blockIdx.x;
  const int xcd = bid & 7;
  const int q = bid >> 3;
  const int cb = (q >> 3) * 8 + xcd;  // coarse bucket, same-XCD siblings
  const int fi = q & 7;
  if (cb >= ncoarse) return;
  const int fb = cb * 8 + fi;          // fine bucket (64 nodes)
  if (fb * 64 >= N) return;
  const int dir = blockIdx.y;
  const int t = threadIdx.x;
  const int* gc = dir ? gc1 : gc0;
  const int* ctail = dir ? ctail1 : ctail0;
  const float* att = dir ? attB : attA;

  for (int i = t; i < ECAP + 24; i += 256) lnbr[i] = 0;
  if (t < 64) {
    hist[t] = 0;
    cur[t] = 0;
  }
  if (t == 64) ecnt = 0;
  __syncthreads();

  // ballot-compacted filter: 1 LDS atomic per wave-iteration
  {
    const int cntc = min(ctail[cb], CC);
    const int* src = gc + cb * CC;
    const int iters = (cntc + 255) >> 8;
    for (int it = 0; it < iters; ++it) {
      int i = it * 256 + t;
      int e = 0;
      bool m = false;
      if (i < cntc) {
        e = src[i];
        m = ((e & 0xFFFF) >> 6) == fb;
      }
      unsigned long long mk = __ballot(m);
      int cnt = __popcll(mk);
      int base = 0;
      if ((t & 63) == 0 && cnt) base = atomicAdd(&ecnt, cnt);
      base = __shfl(base, 0);
      if (m) {
        int pos = base + __popcll(mk & ((1ull << (t & 63)) - 1));
        if (pos < ECAP) ebuf[pos] = e;
      }
    }
  }
  __syncthreads();
  const int tot = min(ecnt, ECAP);
  for (int i = t; i < tot; i += 256) atomicAdd(&hist[ebuf[i] & 63], 1);
  __syncthreads();
  if (t < 64) {  // wave 0: exclusive scan over 64 bins
    int v = hist[t], inc = v;
#pragma unroll
    for (int o = 1; o < 64; o <<= 1) {
      int u = __shfl_up(inc, o);
      if (t >= o) inc += u;
    }
    offs[t] = inc - v;
  }
  __syncthreads();
  for (int i = t; i < tot; i += 256) {
    int e = ebuf[i];
    int r = e & 63;
    lnbr[offs[r] + atomicAdd(&cur[r], 1)] = (int)((unsigned)e >> 16) * 256;
  }
  __syncthreads();

  const int wv = t >> 6, lane = t & 63, g = lane >> 4, jj = lane & 15;
  const float L2E = 1.4426950408889634f;
  float av[8];
  {
    float4 a0 = *(const float4*)(att + jj * 8);
    float4 a1 = *(const float4*)(att + jj * 8 + 4);
    av[0] = a0.x * L2E; av[1] = a0.y * L2E; av[2] = a0.z * L2E; av[3] = a0.w * L2E;
    av[4] = a1.x * L2E; av[5] = a1.y * L2E; av[6] = a1.z * L2E; av[7] = a1.w * L2E;
  }
  const uchar_t* X8b = XL8 + dir * 128 + jj * 8;  // + row byte offset

  for (int r = wv; r < 64; r += 4) {
    const int n = fb * 64 + r;
    if (n >= N) break;
    const char* rowp = (const char*)Y + (size_t)n * 1280 + dir * 640;

    float xi[8];
    {
      short8x v = *(const short8x*)(rowp + 256 + jj * 16);  // xr block (bf16)
#pragma unroll
      for (int q2 = 0; q2 < 8; ++q2) xi[q2] = bf2f((ushort_t)v[q2]);
    }
    float d = 0.f;
    float acc[8];
#pragma unroll
    for (int q2 = 0; q2 < 8; ++q2) acc[q2] = 0.f;

    const int beg = offs[r], deg = hist[r];
    if (deg > 0) {
      int oA = lnbr[beg + g];
      int oB = lnbr[beg + 4 + g];
      uint2 vC = *(const uint2*)(X8b + (size_t)(unsigned)oA);
      uint2 vD = *(const uint2*)(X8b + (size_t)(unsigned)oB);
      for (int k0 = 0; k0 < deg; k0 += 4) {
        int oN = lnbr[beg + k0 + 8 + g];  // zero-filled tail -> safe
        uint2 vN = *(const uint2*)(X8b + (size_t)(unsigned)oN);
        f32x2 x01 = __builtin_amdgcn_cvt_pk_f32_fp8((int)vC.x, false);
        f32x2 x23 = __builtin_amdgcn_cvt_pk_f32_fp8((int)vC.x, true);
        f32x2 x45 = __builtin_amdgcn_cvt_pk_f32_fp8((int)vC.y, false);
        f32x2 x67 = __builtin_amdgcn_cvt_pk_f32_fp8((int)vC.y, true);
        float xj[8] = {x01[0], x01[1], x23[0], x23[1],
                       x45[0], x45[1], x67[0], x67[1]};
        float p = 0.f;
#pragma unroll
        for (int q2 = 0; q2 < 8; ++q2) {
          float e = xi[q2] + xj[q2];
          e = fmaxf(e, 0.2f * e);  // leaky-relu(0.2), slope > 0
          p = fmaf(e, av[q2], p);
        }
        p = dpp_red8(p);  // per-head logit*log2e (lanes 0-7: h0, 8-15: h1)
        float wgt = (k0 + g < deg) ? __builtin_amdgcn_exp2f(p) : 0.f;
        d += wgt;
#pragma unroll
        for (int q2 = 0; q2 < 8; ++q2) acc[q2] = fmaf(xj[q2], wgt, acc[q2]);
        vC = vD;
        vD = vN;
      }
#pragma unroll
      for (int o = 16; o <= 32; o <<= 1) {  // combine the 4 edge-groups
        d += __shfl_xor(d, o);
#pragma unroll
        for (int q2 = 0; q2 < 8; ++q2) acc[q2] += __shfl_xor(acc[q2], o);
      }
    }
    float inv = deg > 0 ? 1.f / d : 0.f;
    float v[8];
#pragma unroll
    for (int q2 = 0; q2 < 8; ++q2) {
      float tq = acc[q2] * inv;
      v[q2] = 0.5f * (tq + __shfl_xor(tq, 8));  // mean over heads
    }
    {
      short8x rv = *(const short8x*)(rowp + 512 + (jj & 7) * 16);  // res block
#pragma unroll
      for (int q2 = 0; q2 < 8; ++q2) v[q2] += bf2f((ushort_t)rv[q2]);
    }

    if (MODE == 0) {
      float s = 0.f;
#pragma unroll
      for (int q2 = 0; q2 < 8; ++q2) s += v[q2];
      s += __shfl_xor(s, 1);
      s += __shfl_xor(s, 2);
      s += __shfl_xor(s, 4);
      float mu = s * (1.f / 64.f);
      float vs = 0.f;
#pragma unroll
      for (int q2 = 0; q2 < 8; ++q2) {
        float dv = v[q2] - mu;
        vs += dv * dv;
      }
      vs += __shfl_xor(vs, 1);
      vs += __shfl_xor(vs, 2);
      vs += __shfl_xor(vs, 4);
      float rstd = rsqrtf(vs * (1.f / 64.f) + 1e-5f);
      if (g == 0 && jj < 8) {
        const float* lg = dir ? lng1 : lng0;
        const float* lb = dir ? lnb1 : lnb0;
        unsigned o2[8];
#pragma unroll
        for (int q2 = 0; q2 < 8; ++q2) {
          int c = jj * 8 + q2;
          float y = (v[q2] - mu) * rstd * lg[c] + lb[c];
          y = fmaxf(y, 0.01f * y);
          o2[q2] = f2bf(y);
        }
        uint4 pk;
        pk.x = o2[0] | (o2[1] << 16);
        pk.y = o2[2] | (o2[3] << 16);
        pk.z = o2[4] | (o2[5] << 16);
        pk.w = o2[6] | (o2[7] << 16);
        *(uint4*)((ushort_t*)outp + (size_t)n * 128 + dir * 64 + jj * 8) = pk;
      }
    } else {
      if (g == 0 && jj < 8) {
        float* op = (float*)outp + (size_t)n * 256 + dir * 64 + jj * 8;
        float4 o0, o1;
        o0.x = fmaxf(v[0], 0.01f * v[0]);
        o0.y = fmaxf(v[1], 0.01f * v[1]);
        o0.z = fmaxf(v[2], 0.01f * v[2]);
        o0.w = fmaxf(v[3], 0.01f * v[3]);
        o1.x = fmaxf(v[4], 0.01f * v[4]);
        o1.y = fmaxf(v[5], 0.01f * v[5]);
        o1.z = fmaxf(v[6], 0.01f * v[6]);
        o1.w = fmaxf(v[7], 0.01f * v[7]);
        *(float4*)op = o0;
        *(float4*)(op + 4) = o1;
      }
    }
  }
}

// ---------------------------------------------------------------------------

extern "C" void kernel_launch(void* const* d_in, const int* in_sizes, int n_in,
                              void* d_out, int out_size, void* d_ws, size_t ws_size,
                              hipStream_t stream) {
  const float* x = (const float*)d_in[0];
  const int* ei = (const int*)d_in[1];
  const int N = in_sizes[0] / 128;
  const int E = in_sizes[1] / 2;
  float* out = (float*)d_out;
  const int ncoarse = (N + (1 << CSHIFT) - 1) >> CSHIFT;

  char* p = (char*)d_ws;
  auto carve = [&](size_t bytes) {
    char* q = p;
    p += ((bytes + 255) & ~(size_t)255);
    return q;
  };
  int* ctail = (int*)carve(2 * NCMAX * 4);
  int* gc0 = (int*)carve((size_t)ncoarse * CC * 4);
  int* gc1 = (int*)carve((size_t)ncoarse * CC * 4);
  ushort_t* Y1 = (ushort_t*)carve((size_t)N * 640 * 2);
  uchar_t* XL8 = (uchar_t*)carve((size_t)N * 256);
  ushort_t* A2 = (ushort_t*)carve((size_t)N * 128 * 2);
  ushort_t* WT1 = (ushort_t*)carve(640 * 128 * 2);
  ushort_t* WT2 = (ushort_t*)carve(640 * 128 * 2);
  float* bc1 = (float*)carve(640 * 4);
  float* bc2 = (float*)carve(640 * 4);
  int* ctail0 = ctail;
  int* ctail1 = ctail + NCMAX;

  auto F = [&](int i) { return (const float*)d_in[i]; };
  GArgs g1, g2;
  g1.Wl[0] = F(2);  g1.bl[0] = F(3);  g1.Wr[0] = F(4);  g1.br[0] = F(5);
  g1.Wres[0] = F(7); g1.bias[0] = F(8);
  g1.Wl[1] = F(9);  g1.bl[1] = F(10); g1.Wr[1] = F(11); g1.br[1] = F(12);
  g1.Wres[1] = F(14); g1.bias[1] = F(15);
  g2.Wl[0] = F(16); g2.bl[0] = F(17); g2.Wr[0] = F(18); g2.br[0] = F(19);
  g2.Wres[0] = F(21); g2.bias[0] = F(22);
  g2.Wl[1] = F(23); g2.bl[1] = F(24); g2.Wr[1] = F(25); g2.br[1] = F(26);
  g2.Wres[1] = F(28); g2.bias[1] = F(29);

  hipMemsetAsync(ctail, 0, 2 * NCMAX * 4, stream);

  pack_kernel<<<1281, 128, 0, stream>>>(g1, g2, WT1, WT2, bc1, bc2);

  const int nbinA = (E + EPB - 1) / EPB;
  const int nrow = (N + 63) / 64;
  const int ngemm = nrow * 5;
  const int ncopy = (N * 32 + 255) / 256;
  k_front<<<nbinA + ngemm + ncopy, 256, 0, stream>>>(
      x, ei, E, N, gc0, gc1, ctail0, ctail1, WT1, bc1, Y1, XL8, out,
      nbinA, ngemm, nrow);

  const int pcb8 = ((ncoarse + 7) / 8) * 8;
  const dim3 ga(pcb8 * 8, 2);
  agg_bucket<0><<<ga, 256, 0, stream>>>(Y1, XL8, gc0, gc1, ctail0, ctail1,
                                        F(6), F(13), F(30), F(31), F(32), F(33),
                                        A2, ncoarse, N);
  gemm2_kernel<<<dim3(nrow, 5), 256, 0, stream>>>(A2, WT2, bc2, Y1, XL8, N);
  agg_bucket<1><<<ga, 256, 0, stream>>>(Y1, XL8, gc0, gc1, ctail0, ctail1,
                                        F(20), F(27), nullptr, nullptr, nullptr,
                                        nullptr, out, ncoarse, N);
}